// Round 12
// baseline (1835.005 us; speedup 1.0000x reference)
//
#include <hip/hip_runtime.h>

#define DEV __device__ __forceinline__
typedef unsigned short us;
typedef __bf16 bf8 __attribute__((ext_vector_type(8)));
typedef float  f4  __attribute__((ext_vector_type(4)));

DEV us f2bf(float f){
  unsigned int u = __builtin_bit_cast(unsigned int, f);
  u = u + 0x7fffu + ((u >> 16) & 1u);
  return (us)(u >> 16);
}
DEV float bf2f(us u){ unsigned int v = ((unsigned int)u) << 16; return __builtin_bit_cast(float, v); }
DEV float sigm(float x){ return 1.f/(1.f + __expf(-x)); }
DEV bf8 ldb(const us* p){ return *reinterpret_cast<const bf8*>(p); }
DEV f4 mfma(bf8 a, bf8 b, f4 c){ return __builtin_amdgcn_mfma_f32_16x16x32_bf16(a, b, c, 0, 0, 0); }

// async global->LDS, 16B per lane: lds dest = wave-uniform base + lane*16,
// global src = per-lane address. (m97 technique: +67% on the GEMM ladder)
DEV void gload16(const us* g, us* l){
  __builtin_amdgcn_global_load_lds(
    (const __attribute__((address_space(1))) unsigned int*)g,
    (__attribute__((address_space(3))) unsigned int*)l, 16, 0, 0);
}

// ---------------- workspace layout (bytes) — total ~236 MB (<246.75 proven safe)
constexpr size_t OFF_WHH0F  = 0;                             // [1536][512] bf16
constexpr size_t OFF_WHH0R  = OFF_WHH0F + 1536ull*512*2;
constexpr size_t OFF_WIH0F  = OFF_WHH0R + 1536ull*512*2;     // [1536][32] bf16
constexpr size_t OFF_WIH0R  = OFF_WIH0F + 1536ull*32*2;
constexpr size_t OFF_WIH1   = OFF_WIH0R + 1536ull*32*2;      // [1536][1024] bf16
constexpr size_t OFF_WHH1   = OFF_WIH1  + 1536ull*1024*2;    // [1536][512] bf16
constexpr size_t OFF_WIH1R  = OFF_WHH1  + 1536ull*512*2;     // [1536][1024] bf16
constexpr size_t OFF_FC1W   = OFF_WIH1R + 1536ull*1024*2;    // [256][1024] bf16
constexpr size_t OFF_FC2W   = OFF_FC1W  + 256ull*1024*2;     // [16][256] bf16
constexpr size_t OFF_BRZ0   = OFF_FC2W  + 16ull*256*2;       // [2][1024] f32
constexpr size_t OFF_BNIH0  = OFF_BRZ0  + 2*1024*4;          // [2][512]
constexpr size_t OFF_BNHH0  = OFF_BNIH0 + 2*512*4;           // [2][512]
constexpr size_t OFF_BRZ1   = OFF_BNHH0 + 2*512*4;           // [1024]
constexpr size_t OFF_BNIH1  = OFF_BRZ1  + 1024*4;            // [512]
constexpr size_t OFF_BNHH1  = OFF_BNIH1 + 512*4;             // [512]
constexpr size_t OFF_BRZ1R  = OFF_BNHH1 + 512*4;             // [1024]
constexpr size_t OFF_BNIH1R = OFF_BRZ1R + 1024*4;            // [512]
constexpr size_t OFF_BNHH1R = OFF_BNIH1R+ 512*4;             // [512]
constexpr size_t OFF_SC2    = OFF_BNHH1R+ 512*4;             // [256]
constexpr size_t OFF_SH2    = OFF_SC2   + 256*4;             // [256]
constexpr size_t OFF_FC2B   = OFF_SH2   + 256*4;             // [16]
constexpr size_t OFF_Y0B    = OFF_FC2B  + 64;                // [4096][28][512] bf16 (= h0b planes)
constexpr size_t OFF_Y0FC   = OFF_Y0B   + 4096ull*28*512*2;  // [4096][4][512] bf16 (= h0f planes)
constexpr size_t OFF_GX     = OFF_Y0FC  + 4096ull*4*512*2;   // [4][4096][1536] bf16
constexpr size_t OFF_H0BF   = OFF_GX    + 4ull*4096*1536*2;  // (unused, kept for layout stability)
constexpr size_t OFF_H0F32  = OFF_H0BF  + 2ull*4096*512*2;   // [4096][512] f32 (l0f cross-launch)
constexpr size_t OFF_H1BF   = OFF_H0F32 + 4096ull*512*4;     // [2pp][4096][512] bf16 (l1f)
constexpr size_t OFF_H1F32  = OFF_H1BF  + 2ull*4096*512*2;   // [4096][512] f32 (l1f cross-launch)
constexpr size_t OFF_H1B    = OFF_H1F32 + 4096ull*512*4;     // [4096][512] bf16
constexpr size_t OFF_XB     = OFF_H1B   + 4096ull*512*2;     // [4096][28][32] bf16 (x pad)
constexpr size_t OFF_BAR    = OFF_XB    + 4096ull*28*32*2;   // flag slots

// flags: slot = 16 groups x 64 u32 (group line padded to 256B). 3 slots used
// (A / l0f / l1f); flags are MONOTONE within a run -> rocprof replays safe.
constexpr int FL_GRP  = 64;            // u32 per group
constexpr int FL_SLOT = 16*FL_GRP;     // u32 per slot
constexpr int FL_TOTAL= 16*FL_SLOT;    // zero generous region

constexpr long PPH   = 4096ll*512;     // h ping-pong plane (elems)
constexpr long PLANE = 4096ll*1536;    // gx per-t plane (elems)

// ---------------- K0: weight/bias prep + x->bf16 pad + flag zero ----------------
__global__ void prep_kernel(
  const float* __restrict__ x,
  const float* __restrict__ Wih0, const float* __restrict__ Whh0,
  const float* __restrict__ bih0, const float* __restrict__ bhh0,
  const float* __restrict__ Wih0r,const float* __restrict__ Whh0r,
  const float* __restrict__ bih0r,const float* __restrict__ bhh0r,
  const float* __restrict__ Wih1, const float* __restrict__ Whh1,
  const float* __restrict__ bih1, const float* __restrict__ bhh1,
  const float* __restrict__ Wih1r,const float* __restrict__ bih1r,
  const float* __restrict__ bhh1r,
  const float* __restrict__ fc1w, const float* __restrict__ fc1b,
  const float* __restrict__ gma,  const float* __restrict__ bta,
  const float* __restrict__ mean, const float* __restrict__ var,
  const float* __restrict__ fc2w, const float* __restrict__ fc2b,
  us* __restrict__ whh0f, us* __restrict__ whh0r,
  us* __restrict__ wih0f, us* __restrict__ wih0r,
  us* __restrict__ wih1,  us* __restrict__ whh1, us* __restrict__ wih1r,
  us* __restrict__ fc1wb, us* __restrict__ fc2wp,
  float* __restrict__ brz0, float* __restrict__ bnih0, float* __restrict__ bnhh0,
  float* __restrict__ brz1, float* __restrict__ bnih1, float* __restrict__ bnhh1,
  float* __restrict__ brz1r,float* __restrict__ bnih1r,float* __restrict__ bnhh1r,
  float* __restrict__ sc2,  float* __restrict__ sh2,   float* __restrict__ fc2bp,
  us* __restrict__ xbp, unsigned* __restrict__ flp)
{
  const int tid = blockIdx.x * blockDim.x + threadIdx.x;
  const int np  = gridDim.x * blockDim.x;
  for (int i = tid; i < 1536*512; i += np){
    whh0f[i] = f2bf(Whh0[i]);
    whh0r[i] = f2bf(Whh0r[i]);
    whh1[i]  = f2bf(Whh1[i]);
  }
  for (int i = tid; i < 1536*32; i += np){
    int n = i >> 5, k = i & 31;
    wih0f[i] = (k < 28) ? f2bf(Wih0[n*28 + k])  : (us)0;
    wih0r[i] = (k < 28) ? f2bf(Wih0r[n*28 + k]) : (us)0;
  }
  for (int i = tid; i < 1536*1024; i += np){
    wih1[i]  = f2bf(Wih1[i]);
    wih1r[i] = f2bf(Wih1r[i]);
  }
  for (int i = tid; i < 256*1024; i += np) fc1wb[i] = f2bf(fc1w[i]);
  for (int i = tid; i < 16*256;   i += np){
    int n = i / 256; fc2wp[i] = (n < 10) ? f2bf(fc2w[i]) : (us)0;
  }
  // x -> bf16, 28 cols padded to 32 (row = (m,t))
  for (int i = tid; i < 4096*28; i += np){
    const float* src = x + (size_t)i * 28;
    us* dst = xbp + (size_t)i * 32;
    #pragma unroll
    for (int k = 0; k < 28; ++k) dst[k] = f2bf(src[k]);
    dst[28] = dst[29] = dst[30] = dst[31] = 0;
  }
  for (int i = tid; i < FL_TOTAL; i += np) flp[i] = 0;  // re-zeroed each run
  for (int i = tid; i < 1024; i += np){
    brz0[i]        = bih0[i]  + bhh0[i];
    brz0[1024 + i] = bih0r[i] + bhh0r[i];
    brz1[i]        = bih1[i]  + bhh1[i];
    brz1r[i]       = bih1r[i] + bhh1r[i];
  }
  for (int i = tid; i < 512; i += np){
    bnih0[i]       = bih0[1024 + i];   bnhh0[i]       = bhh0[1024 + i];
    bnih0[512 + i] = bih0r[1024 + i];  bnhh0[512 + i] = bhh0r[1024 + i];
    bnih1[i]       = bih1[1024 + i];   bnhh1[i]       = bhh1[1024 + i];
    bnih1r[i]      = bih1r[1024 + i];  bnhh1r[i]      = bhh1r[1024 + i];
  }
  for (int i = tid; i < 256; i += np){
    float s = gma[i] * rsqrtf(var[i] + 1e-5f);
    sc2[i] = s;
    sh2[i] = (fc1b[i] - mean[i]) * s + bta[i];
  }
  for (int i = tid; i < 16; i += np) fc2bp[i] = (i < 10) ? fc2b[i] : 0.f;
}

// ---------------- big GEMM: C[sl][m][1536] = A @ B^T (bf16, no bias) ----------------
// m97 structure (verified round 8: 125 -> ~77 µs): 128x128 tile, 256 thr / 4
// waves (wave tile 64x64, acc[4][4]); A and B staged via global_load_lds
// width-16 into linear LDS, double-buffered; one barrier per K-step.
__global__ __launch_bounds__(256) void gemm_kernel(
  const us* __restrict__ s0, long s0m, long s0t, int K0,
  const us* __restrict__ s1, long s1m, long s1t,
  const us* __restrict__ B, int Kw, int nk, int tshift, int nMtiles,
  us* __restrict__ C, long cT)
{
  __shared__ __align__(16) us As[2*128*32];
  __shared__ __align__(16) us Bs[2*128*32];

  const int tid = threadIdx.x, bid = blockIdx.x;
  const int mtile = bid % nMtiles, ntile = bid / nMtiles;
  const int Mbase = mtile * 128, Nbase = ntile * 128;
  const int mask = (1 << tshift) - 1;
  const int ktSplit = K0 >> 5;

  const int w = tid >> 6, lane = tid & 63, ln = lane & 15, lq = lane >> 4;
  const int wm = w >> 1, wn = w & 1;

  const int r0 = tid >> 2, g0 = tid & 3;
  const int R0 = Mbase + r0, R1 = R0 + 64;
  const int m0 = R0 >> tshift, sl0 = R0 & mask;
  const int m1 = R1 >> tshift, sl1 = R1 & mask;
  const us* pA00 = s0 + (size_t)m0*s0m + (long)sl0*s0t + g0*8;   // kt < ktSplit
  const us* pA01 = s1 + (size_t)m0*s1m + (long)sl0*s1t + g0*8;   // kt >= ktSplit
  const us* pA10 = s0 + (size_t)m1*s0m + (long)sl1*s0t + g0*8;
  const us* pA11 = s1 + (size_t)m1*s1m + (long)sl1*s1t + g0*8;
  const us* pB0  = B + (size_t)(Nbase + r0     )*Kw + g0*8;
  const us* pB1  = B + (size_t)(Nbase + r0 + 64)*Kw + g0*8;

  auto stage = [&](int buf, int kt){
    const int kc = kt*32;
    const us* a0; const us* a1;
    if (kt < ktSplit){ a0 = pA00 + kc; a1 = pA10 + kc; }
    else             { a0 = pA01 + (kc - K0); a1 = pA11 + (kc - K0); }
    gload16(a0,       &As[buf +        w*512]);
    gload16(a1,       &As[buf + 2048 + w*512]);
    gload16(pB0 + kc, &Bs[buf +        w*512]);
    gload16(pB1 + kc, &Bs[buf + 2048 + w*512]);
  };

  stage(0, 0);
  __syncthreads();    // compiler emits vmcnt(0) before the barrier

  f4 acc[4][4] = {};

  for (int kt = 0; kt < nk; ++kt){
    const int buf = (kt & 1) * 4096;
    const bool more = (kt + 1) < nk;
    if (more) stage(buf ^ 4096, kt + 1);
    bf8 a0 = ldb(&As[buf + (wm*64 +  0 + ln)*32 + lq*8]);
    bf8 a1 = ldb(&As[buf + (wm*64 + 16 + ln)*32 + lq*8]);
    bf8 a2 = ldb(&As[buf + (wm*64 + 32 + ln)*32 + lq*8]);
    bf8 a3 = ldb(&As[buf + (wm*64 + 48 + ln)*32 + lq*8]);
    bf8 b0 = ldb(&Bs[buf + (wn*64 +  0 + ln)*32 + lq*8]);
    bf8 b1 = ldb(&Bs[buf + (wn*64 + 16 + ln)*32 + lq*8]);
    bf8 b2 = ldb(&Bs[buf + (wn*64 + 32 + ln)*32 + lq*8]);
    bf8 b3 = ldb(&Bs[buf + (wn*64 + 48 + ln)*32 + lq*8]);
    acc[0][0] = mfma(a0, b0, acc[0][0]); acc[0][1] = mfma(a0, b1, acc[0][1]);
    acc[0][2] = mfma(a0, b2, acc[0][2]); acc[0][3] = mfma(a0, b3, acc[0][3]);
    acc[1][0] = mfma(a1, b0, acc[1][0]); acc[1][1] = mfma(a1, b1, acc[1][1]);
    acc[1][2] = mfma(a1, b2, acc[1][2]); acc[1][3] = mfma(a1, b3, acc[1][3]);
    acc[2][0] = mfma(a2, b0, acc[2][0]); acc[2][1] = mfma(a2, b1, acc[2][1]);
    acc[2][2] = mfma(a2, b2, acc[2][2]); acc[2][3] = mfma(a2, b3, acc[2][3]);
    acc[3][0] = mfma(a3, b0, acc[3][0]); acc[3][1] = mfma(a3, b1, acc[3][1]);
    acc[3][2] = mfma(a3, b2, acc[3][2]); acc[3][3] = mfma(a3, b3, acc[3][3]);
    if (more) __syncthreads();   // drains next-buf gloads; guards buf reuse
  }

  #pragma unroll
  for (int mtf = 0; mtf < 4; ++mtf){
    #pragma unroll
    for (int ntf = 0; ntf < 4; ++ntf){
      const int col = Nbase + wn*64 + ntf*16 + ln;
      #pragma unroll
      for (int e = 0; e < 4; ++e){
        const int R = Mbase + wm*64 + mtf*16 + lq*4 + e;
        const int m = R >> tshift, sl = R & mask;
        C[(size_t)sl*cT + (size_t)m*1536 + col] = f2bf(acc[mtf][ntf][e]);
      }
    }
  }
}

// ---------------- persistent GRU scan: nsteps serial steps, Whh pinned in LDS ----
// BARRIER-FREE K-loop: wave w consumes ONLY its own 32 M-rows of A, so A is
// loaded per-lane directly from global (XCD-L2-resident h planes) with a
// dist-3 register pipeline — no LDS staging, no per-kt __syncthreads (16
// barriers/step removed; waves slip freely and hide L2 latency). Ws/Wxs are
// read-only after ONE one-time barrier. Flag barrier per step unchanged
// (monotone per-block flags, 16-lane poll, watchdog).
template<int USE_X>
__global__ __launch_bounds__(512) void gru_coop_kernel(
  const us* __restrict__ W, const us* __restrict__ Wx,
  const us* __restrict__ xb, const us* __restrict__ gxAll,
  us* __restrict__ hPP, float* __restrict__ hF,
  us* __restrict__ y, long ymstride, int ymode,
  const float* __restrict__ brz, const float* __restrict__ bni,
  const float* __restrict__ bnh,
  int s0, int nsteps, int rev, unsigned* __restrict__ flags)
{
  __shared__ us Ws[96*520];
  __shared__ us Wxs[96*40];

  const int tid = threadIdx.x, bid = blockIdx.x;
  const int hcb = bid >> 4, nm = bid & 15;
  const size_t Mbase = (size_t)nm * 256;
  const int hcBase = hcb * 32;
  const int w = tid >> 6, lane = tid & 63, ln = lane & 15, lq = lane >> 4;
  unsigned* const fl = flags + nm * FL_GRP;

  #pragma unroll
  for (int i = 0; i < 12; ++i){
    const int q = tid + i*512;
    const int rl = q >> 6, seg = q & 63;
    const int grow = (rl >> 5)*512 + hcBase + (rl & 31);
    *reinterpret_cast<uint4*>(&Ws[rl*520 + seg*8]) =
      *reinterpret_cast<const uint4*>(&W[(size_t)grow*512 + seg*8]);
  }
  if (USE_X && tid < 384){
    const int rl = tid >> 2, seg = tid & 3;
    const int grow = (rl >> 5)*512 + hcBase + (rl & 31);
    *reinterpret_cast<uint4*>(&Wxs[rl*40 + seg*8]) =
      *reinterpret_cast<const uint4*>(&Wx[(size_t)grow*32 + seg*8]);
  }
  __syncthreads();   // one-time: Ws/Wxs visible to all waves (read-only after)

  float hreg[2][2][4];
  #pragma unroll
  for (int nt = 0; nt < 2; ++nt)
    #pragma unroll
    for (int mt = 0; mt < 2; ++mt)
      #pragma unroll
      for (int e = 0; e < 4; ++e) hreg[nt][mt][e] = 0.f;
  if (s0 > 0){
    #pragma unroll
    for (int nt = 0; nt < 2; ++nt){
      const int ch = hcBase + nt*16 + ln;
      #pragma unroll
      for (int mt = 0; mt < 2; ++mt)
        #pragma unroll
        for (int e = 0; e < 4; ++e){
          const size_t m = Mbase + w*32 + mt*16 + lq*4 + e;
          hreg[nt][mt][e] = hF[m*512 + ch];
        }
    }
  }

  for (int s = s0; s < s0 + nsteps; ++s){
    const int t = rev ? 27 - s : s;
    const bool first = (s == 0);
    const bool last  = (s == s0 + nsteps - 1);

    const us* hin; long hinm;
    us* hOut = nullptr;
    if (ymode == 1){ hin = y + (size_t)(rev ? t + 1 : t - 1) * 512; hinm = ymstride; }
    else if (ymode == 2){ hin = y + (size_t)((s - 1) & 3) * 512; hinm = ymstride; }
    else {
      hin  = hPP + (size_t)(s & 1) * PPH; hinm = 512;
      hOut = hPP + (size_t)((s & 1) ^ 1) * PPH;
    }

    f4 acc[3][2][2] = {};
    f4 accNX[2][2] = {};

    us gxv[12][4];
    if (!USE_X){
      const us* gx = gxAll + (size_t)(s - s0) * PLANE;
      #pragma unroll
      for (int nt = 0; nt < 2; ++nt){
        const int ch = hcBase + nt*16 + ln;
        #pragma unroll
        for (int mt = 0; mt < 2; ++mt){
          #pragma unroll
          for (int e = 0; e < 4; ++e){
            const size_t m = Mbase + w*32 + mt*16 + lq*4 + e;
            const us* gxr = gx + m*1536;
            gxv[0 + nt*2 + mt][e] = gxr[ch];
            gxv[4 + nt*2 + mt][e] = gxr[512 + ch];
            gxv[8 + nt*2 + mt][e] = gxr[1024 + ch];
          }
        }
      }
    }

    // ---- x-projection K-tile (K=32): per-lane direct global loads, Wxs pinned
    if (USE_X){
      bf8 ax0 = ldb(&xb[((Mbase + w*32 +  0 + ln)*28 + (size_t)t)*32 + lq*8]);
      bf8 ax1 = ldb(&xb[((Mbase + w*32 + 16 + ln)*28 + (size_t)t)*32 + lq*8]);
      #pragma unroll
      for (int g = 0; g < 3; ++g){
        #pragma unroll
        for (int nt = 0; nt < 2; ++nt){
          bf8 b = ldb(&Wxs[(g*32 + nt*16 + ln)*40 + lq*8]);
          if (g == 2){
            accNX[nt][0] = mfma(ax0, b, accNX[nt][0]);
            accNX[nt][1] = mfma(ax1, b, accNX[nt][1]);
          } else {
            acc[g][nt][0] = mfma(ax0, b, acc[g][nt][0]);
            acc[g][nt][1] = mfma(ax1, b, acc[g][nt][1]);
          }
        }
      }
    }

    // ---- h @ Whh^T, 16 K-tiles, A direct-from-global, dist-3 reg pipeline
    if (!first){
      auto ldA = [&](int kt, int r16) -> bf8 {
        return ldb(&hin[(Mbase + w*32 + r16 + ln)*hinm + kt*32 + lq*8]);
      };
      bf8 f0a = ldA(0, 0), f0b = ldA(0, 16);
      bf8 f1a = ldA(1, 0), f1b = ldA(1, 16);
      bf8 f2a = ldA(2, 0), f2b = ldA(2, 16);
      #pragma unroll
      for (int kt = 0; kt < 16; ++kt){
        bf8 a0 = f0a, a1 = f0b;
        f0a = f1a; f0b = f1b; f1a = f2a; f1b = f2b;
        if (kt + 3 < 16){ f2a = ldA(kt + 3, 0); f2b = ldA(kt + 3, 16); }
        const int kc = kt*32 + lq*8;
        #pragma unroll
        for (int g = 0; g < 3; ++g){
          #pragma unroll
          for (int nt = 0; nt < 2; ++nt){
            bf8 b = ldb(&Ws[(g*32 + nt*16 + ln)*520 + kc]);
            acc[g][nt][0] = mfma(a0, b, acc[g][nt][0]);
            acc[g][nt][1] = mfma(a1, b, acc[g][nt][1]);
          }
        }
      }
    }

    #pragma unroll
    for (int nt = 0; nt < 2; ++nt){
      const int ch = hcBase + nt*16 + ln;
      const float br = brz[ch], bz = brz[512 + ch], bi = bni[ch], bh = bnh[ch];
      #pragma unroll
      for (int mt = 0; mt < 2; ++mt){
        #pragma unroll
        for (int e = 0; e < 4; ++e){
          const size_t m = Mbase + w*32 + mt*16 + lq*4 + e;
          float rr = acc[0][nt][mt][e] + br;
          float zz = acc[1][nt][mt][e] + bz;
          float xr = accNX[nt][mt][e];
          if (!USE_X){
            rr += bf2f(gxv[0 + nt*2 + mt][e]);
            zz += bf2f(gxv[4 + nt*2 + mt][e]);
            xr += bf2f(gxv[8 + nt*2 + mt][e]);
          }
          float r = sigm(rr);
          float z = sigm(zz);
          float n = tanhf(xr + bi + r*(acc[2][nt][mt][e] + bh));
          float hprev = first ? 0.f : hreg[nt][mt][e];
          float h = (1.f - z)*n + z*hprev;
          hreg[nt][mt][e] = h;
          if (last && hF) hF[m*512 + ch] = h;
          us hb = f2bf(h);
          if (ymode == 0)      hOut[m*512 + ch] = hb;
          else if (ymode == 1) y[m*ymstride + (size_t)t*512 + ch] = hb;
          else                 y[m*ymstride + (size_t)(s - s0)*512 + ch] = hb;
        }
      }
    }

    if (!last){
      __syncthreads();   // every wave: vmcnt(0)+barrier -> all stores in XCD L2
      if (tid < 16){
        if (tid == 0)
          __hip_atomic_store(fl + hcb, (unsigned)(s + 1),
                             __ATOMIC_RELAXED, __HIP_MEMORY_SCOPE_AGENT);
        const unsigned tgt = (unsigned)(s + 1);
        int guard = 0;
        while (__hip_atomic_load(fl + tid, __ATOMIC_RELAXED,
                                 __HIP_MEMORY_SCOPE_AGENT) < tgt){
          __builtin_amdgcn_s_sleep(1);
          if (++guard > (1 << 18)) break;   // watchdog: never hang the queue
        }
      }
      __syncthreads();
    }
  }
}

// ---------------- l1 backward single step: elementwise gates from gxb (h=0) ----
__global__ void gate1b_kernel(
  const us* __restrict__ gxb, const float* __restrict__ brz,
  const float* __restrict__ bni, const float* __restrict__ bnh,
  us* __restrict__ h1b)
{
  const int i = blockIdx.x * blockDim.x + threadIdx.x;
  if (i >= 4096*512) return;
  const int m = i >> 9, ch = i & 511;
  const us* g = gxb + (size_t)m*1536;
  float r = sigm(bf2f(g[ch]) + brz[ch]);
  float z = sigm(bf2f(g[512 + ch]) + brz[512 + ch]);
  float n = tanhf(bf2f(g[1024 + ch]) + bni[ch] + r*bnh[ch]);
  h1b[i] = f2bf((1.f - z)*n);
}

// ---------------- head: [h1f|h1b] -> fc1 -> bn/relu -> fc2 -> log_softmax ----
__global__ __launch_bounds__(512) void head_kernel(
  const us* __restrict__ h1f, const us* __restrict__ h1b,
  const us* __restrict__ fc1w, const us* __restrict__ fc2wp,
  const float* __restrict__ sc2, const float* __restrict__ sh2,
  const float* __restrict__ fc2b, float* __restrict__ out)
{
  constexpr int APS = 1048;
  __shared__ us As[32 * APS];
  __shared__ us actS[32 * 264];
  __shared__ float lg[32 * 16];
  const int tid = threadIdx.x;
  const size_t row0 = (size_t)blockIdx.x * 32;
  const int w = tid >> 6, lane = tid & 63, ln = lane & 15, lq = lane >> 4;

  for (int i = tid; i < 32*128; i += 512){
    int r = i >> 7, g = i & 127, col = g*8;
    uint4 v = (col < 512)
      ? *reinterpret_cast<const uint4*>(h1f + (row0 + r)*512 + col)
      : *reinterpret_cast<const uint4*>(h1b + (row0 + r)*512 + (col - 512));
    *reinterpret_cast<uint4*>(&As[r*APS + col]) = v;
  }
  __syncthreads();

  {
    f4 acc[2][2] = {};
    for (int kt = 0; kt < 32; ++kt){
      const int kc = kt*32 + lq*8;
      bf8 a0 = ldb(&As[ln*APS + kc]);
      bf8 a1 = ldb(&As[(16 + ln)*APS + kc]);
      #pragma unroll
      for (int nt = 0; nt < 2; ++nt){
        const int col = w*32 + nt*16 + ln;
        bf8 b = ldb(&fc1w[(size_t)col*1024 + kc]);
        acc[0][nt] = mfma(a0, b, acc[0][nt]);
        acc[1][nt] = mfma(a1, b, acc[1][nt]);
      }
    }
    #pragma unroll
    for (int nt = 0; nt < 2; ++nt){
      const int col = w*32 + nt*16 + ln;
      const float sc = sc2[col], sh = sh2[col];
      #pragma unroll
      for (int mt = 0; mt < 2; ++mt)
        #pragma unroll
        for (int e = 0; e < 4; ++e){
          float v = fmaxf(acc[mt][nt][e]*sc + sh, 0.f);
          actS[(mt*16 + lq*4 + e)*264 + col] = f2bf(v);
        }
    }
    __syncthreads();
  }

  if (w == 0){
    f4 acc[2] = {};
    for (int kt = 0; kt < 8; ++kt){
      const int kc = kt*32 + lq*8;
      bf8 a0 = ldb(&actS[ln*264 + kc]);
      bf8 a1 = ldb(&actS[(16 + ln)*264 + kc]);
      bf8 b  = ldb(&fc2wp[ln*256 + kc]);
      acc[0] = mfma(a0, b, acc[0]);
      acc[1] = mfma(a1, b, acc[1]);
    }
    const float bb = fc2b[ln];
    #pragma unroll
    for (int mt = 0; mt < 2; ++mt)
      #pragma unroll
      for (int e = 0; e < 4; ++e)
        lg[(mt*16 + lq*4 + e)*16 + ln] = acc[mt][e] + bb;
  }
  __syncthreads();
  if (tid < 32){
    const int r = tid;
    float mx = -1e30f;
    for (int cc = 0; cc < 10; ++cc) mx = fmaxf(mx, lg[r*16 + cc]);
    float sum = 0.f;
    for (int cc = 0; cc < 10; ++cc) sum += __expf(lg[r*16 + cc] - mx);
    const float lse = mx + logf(sum);
    for (int cc = 0; cc < 10; ++cc)
      out[(row0 + r)*10 + cc] = lg[r*16 + cc] - lse;
  }
}

// ---------------- launch ----------------
extern "C" void kernel_launch(void* const* d_in, const int* in_sizes, int n_in,
                              void* d_out, int out_size, void* d_ws, size_t ws_size,
                              hipStream_t stream)
{
  (void)in_sizes; (void)n_in; (void)out_size; (void)ws_size;
  char* ws = (char*)d_ws;
  auto US = [&](size_t off){ return (us*)(ws + off); };
  auto FP = [&](size_t off){ return (float*)(ws + off); };

  const float* x      = (const float*)d_in[0];
  const float* Wih0   = (const float*)d_in[1];
  const float* Whh0   = (const float*)d_in[2];
  const float* bih0   = (const float*)d_in[3];
  const float* bhh0   = (const float*)d_in[4];
  const float* Wih0r  = (const float*)d_in[5];
  const float* Whh0r  = (const float*)d_in[6];
  const float* bih0r  = (const float*)d_in[7];
  const float* bhh0r  = (const float*)d_in[8];
  const float* Wih1   = (const float*)d_in[9];
  const float* Whh1   = (const float*)d_in[10];
  const float* bih1   = (const float*)d_in[11];
  const float* bhh1   = (const float*)d_in[12];
  const float* Wih1r  = (const float*)d_in[13];
  // d_in[14] (W_hh_l1r) unused: backward layer-1 runs exactly one step from h=0.
  const float* bih1r  = (const float*)d_in[15];
  const float* bhh1r  = (const float*)d_in[16];
  const float* fc1w   = (const float*)d_in[17];
  const float* fc1b   = (const float*)d_in[18];
  const float* gma    = (const float*)d_in[19];
  const float* bta    = (const float*)d_in[20];
  const float* mean   = (const float*)d_in[21];
  const float* var    = (const float*)d_in[22];
  const float* fc2w   = (const float*)d_in[23];
  const float* fc2b   = (const float*)d_in[24];

  prep_kernel<<<512, 256, 0, stream>>>(
    x, Wih0, Whh0, bih0, bhh0, Wih0r, Whh0r, bih0r, bhh0r,
    Wih1, Whh1, bih1, bhh1, Wih1r, bih1r, bhh1r,
    fc1w, fc1b, gma, bta, mean, var, fc2w, fc2b,
    US(OFF_WHH0F), US(OFF_WHH0R), US(OFF_WIH0F), US(OFF_WIH0R),
    US(OFF_WIH1), US(OFF_WHH1), US(OFF_WIH1R), US(OFF_FC1W), US(OFF_FC2W),
    FP(OFF_BRZ0), FP(OFF_BNIH0), FP(OFF_BNHH0),
    FP(OFF_BRZ1), FP(OFF_BNIH1), FP(OFF_BNHH1),
    FP(OFF_BRZ1R), FP(OFF_BNIH1R), FP(OFF_BNHH1R),
    FP(OFF_SC2), FP(OFF_SH2), FP(OFF_FC2B),
    US(OFF_XB), (unsigned*)(ws + OFF_BAR));

  us* y0b  = US(OFF_Y0B);
  us* y0fc = US(OFF_Y0FC);
  us* gx   = US(OFF_GX);
  us* h1bf = US(OFF_H1BF);
  us* xb   = US(OFF_XB);
  unsigned* fl = (unsigned*)(ws + OFF_BAR);

  // ---- phase A: layer-0 backward — one persistent launch; h lives in y0b slices
  gru_coop_kernel<1><<<256, 512, 0, stream>>>(
    US(OFF_WHH0R), US(OFF_WIH0R), xb, nullptr,
    nullptr, nullptr, y0b, 28ll*512, 1,
    FP(OFF_BRZ0) + 1024, FP(OFF_BNIH0) + 512, FP(OFF_BNHH0) + 512,
    0, 28, 1, fl + 0*FL_SLOT);

  // ---- phase B: l0f chunk (h in y0fc ring) + gx1 gemm + l1f chunk ----
  for (int c = 0; c < 7; ++c){
    const int t0 = 4*c;
    gru_coop_kernel<1><<<256, 512, 0, stream>>>(
      US(OFF_WHH0F), US(OFF_WIH0F), xb, nullptr,
      nullptr, FP(OFF_H0F32), y0fc, 4ll*512, 2,
      FP(OFF_BRZ0), FP(OFF_BNIH0), FP(OFF_BNHH0),
      t0, 4, 0, fl + 1*FL_SLOT);
    // gx1[sl] = [y0fc[:,sl,:] | y0b[:,t0+sl,:]] @ Wih1^T  (K=1024, nk=32)
    gemm_kernel<<<128*12, 256, 0, stream>>>(
      y0fc, 4ll*512, 512, 512,
      y0b + t0*512, 28ll*512, 512,
      US(OFF_WIH1), 1024, 32, 2, 128, gx, PLANE);
    gru_coop_kernel<0><<<256, 512, 0, stream>>>(
      US(OFF_WHH1), nullptr, nullptr, gx,
      h1bf, FP(OFF_H1F32), nullptr, 0, 0,
      FP(OFF_BRZ1), FP(OFF_BNIH1), FP(OFF_BNHH1),
      t0, 4, 0, fl + 2*FL_SLOT);
  }

  // ---- layer-1 backward: gxb = [h0f_27 | y0b_27] @ Wih1r^T, then gates (h=0) ----
  // h0f final state (t=27) = y0fc slice 3 after the last l0f chunk.
  gemm_kernel<<<32*12, 256, 0, stream>>>(
    y0fc + 3*512, 4ll*512, 0, 512,
    y0b + 27*512, 28ll*512, 0,
    US(OFF_WIH1R), 1024, 32, 0, 32, gx, 0);
  gate1b_kernel<<<8192, 256, 0, stream>>>(
    gx, FP(OFF_BRZ1R), FP(OFF_BNIH1R), FP(OFF_BNHH1R), US(OFF_H1B));

  // ---- head (h1f final is pp buffer 0 after 28 steps) ----
  head_kernel<<<128, 512, 0, stream>>>(
    h1bf, US(OFF_H1B), US(OFF_FC1W), US(OFF_FC2W),
    FP(OFF_SC2), FP(OFF_SH2), FP(OFF_FC2B), (float*)d_out);
}

// Round 13
// 1689.389 us; speedup vs baseline: 1.0862x; 1.0862x over previous
//
#include <hip/hip_runtime.h>

#define DEV __device__ __forceinline__
typedef unsigned short us;
typedef __bf16 bf8 __attribute__((ext_vector_type(8)));
typedef float  f4  __attribute__((ext_vector_type(4)));

DEV us f2bf(float f){
  unsigned int u = __builtin_bit_cast(unsigned int, f);
  u = u + 0x7fffu + ((u >> 16) & 1u);
  return (us)(u >> 16);
}
DEV float bf2f(us u){ unsigned int v = ((unsigned int)u) << 16; return __builtin_bit_cast(float, v); }
DEV float sigm(float x){ return 1.f/(1.f + __expf(-x)); }
DEV bf8 ldb(const us* p){ return *reinterpret_cast<const bf8*>(p); }
DEV f4 mfma(bf8 a, bf8 b, f4 c){ return __builtin_amdgcn_mfma_f32_16x16x32_bf16(a, b, c, 0, 0, 0); }

// async global->LDS, 16B per lane: lds dest = wave-uniform base + lane*16,
// global src = per-lane address. (m97 technique: +67% on the GEMM ladder)
DEV void gload16(const us* g, us* l){
  __builtin_amdgcn_global_load_lds(
    (const __attribute__((address_space(1))) unsigned int*)g,
    (__attribute__((address_space(3))) unsigned int*)l, 16, 0, 0);
}

// ---------------- workspace layout (bytes) — total ~236 MB (<246.75 proven safe)
constexpr size_t OFF_WHH0F  = 0;                             // [1536][512] bf16
constexpr size_t OFF_WHH0R  = OFF_WHH0F + 1536ull*512*2;
constexpr size_t OFF_WIH0F  = OFF_WHH0R + 1536ull*512*2;     // [1536][32] bf16
constexpr size_t OFF_WIH0R  = OFF_WIH0F + 1536ull*32*2;
constexpr size_t OFF_WIH1   = OFF_WIH0R + 1536ull*32*2;      // [1536][1024] bf16
constexpr size_t OFF_WHH1   = OFF_WIH1  + 1536ull*1024*2;    // [1536][512] bf16
constexpr size_t OFF_WIH1R  = OFF_WHH1  + 1536ull*512*2;     // [1536][1024] bf16
constexpr size_t OFF_FC1W   = OFF_WIH1R + 1536ull*1024*2;    // [256][1024] bf16
constexpr size_t OFF_FC2W   = OFF_FC1W  + 256ull*1024*2;     // [16][256] bf16
constexpr size_t OFF_BRZ0   = OFF_FC2W  + 16ull*256*2;       // [2][1024] f32
constexpr size_t OFF_BNIH0  = OFF_BRZ0  + 2*1024*4;          // [2][512]
constexpr size_t OFF_BNHH0  = OFF_BNIH0 + 2*512*4;           // [2][512]
constexpr size_t OFF_BRZ1   = OFF_BNHH0 + 2*512*4;           // [1024]
constexpr size_t OFF_BNIH1  = OFF_BRZ1  + 1024*4;            // [512]
constexpr size_t OFF_BNHH1  = OFF_BNIH1 + 512*4;             // [512]
constexpr size_t OFF_BRZ1R  = OFF_BNHH1 + 512*4;             // [1024]
constexpr size_t OFF_BNIH1R = OFF_BRZ1R + 1024*4;            // [512]
constexpr size_t OFF_BNHH1R = OFF_BNIH1R+ 512*4;             // [512]
constexpr size_t OFF_SC2    = OFF_BNHH1R+ 512*4;             // [256]
constexpr size_t OFF_SH2    = OFF_SC2   + 256*4;             // [256]
constexpr size_t OFF_FC2B   = OFF_SH2   + 256*4;             // [16]
constexpr size_t OFF_Y0B    = OFF_FC2B  + 64;                // [4096][28][512] bf16 (= h0b planes)
constexpr size_t OFF_Y0FC   = OFF_Y0B   + 4096ull*28*512*2;  // [4096][4][512] bf16 (= h0f planes)
constexpr size_t OFF_GX     = OFF_Y0FC  + 4096ull*4*512*2;   // [4][4096][1536] bf16
constexpr size_t OFF_H0BF   = OFF_GX    + 4ull*4096*1536*2;  // (unused, kept for layout stability)
constexpr size_t OFF_H0F32  = OFF_H0BF  + 2ull*4096*512*2;   // [4096][512] f32 (l0f cross-launch)
constexpr size_t OFF_H1BF   = OFF_H0F32 + 4096ull*512*4;     // [2pp][4096][512] bf16 (l1f)
constexpr size_t OFF_H1F32  = OFF_H1BF  + 2ull*4096*512*2;   // [4096][512] f32 (l1f cross-launch)
constexpr size_t OFF_H1B    = OFF_H1F32 + 4096ull*512*4;     // [4096][512] bf16
constexpr size_t OFF_XB     = OFF_H1B   + 4096ull*512*2;     // [4096][28][32] bf16 (x pad)
constexpr size_t OFF_BAR    = OFF_XB    + 4096ull*28*32*2;   // flag slots

// flags: slot = 16 groups x 64 u32 (group line padded to 256B). 3 slots used
// (A / l0f / l1f); flags are MONOTONE within a run -> rocprof replays safe.
constexpr int FL_GRP  = 64;            // u32 per group
constexpr int FL_SLOT = 16*FL_GRP;     // u32 per slot
constexpr int FL_TOTAL= 16*FL_SLOT;    // zero generous region

constexpr long PPH   = 4096ll*512;     // h ping-pong plane (elems)
constexpr long PLANE = 4096ll*1536;    // gx per-t plane (elems)

// ---------------- K0: weight/bias prep + x->bf16 pad + flag zero ----------------
__global__ void prep_kernel(
  const float* __restrict__ x,
  const float* __restrict__ Wih0, const float* __restrict__ Whh0,
  const float* __restrict__ bih0, const float* __restrict__ bhh0,
  const float* __restrict__ Wih0r,const float* __restrict__ Whh0r,
  const float* __restrict__ bih0r,const float* __restrict__ bhh0r,
  const float* __restrict__ Wih1, const float* __restrict__ Whh1,
  const float* __restrict__ bih1, const float* __restrict__ bhh1,
  const float* __restrict__ Wih1r,const float* __restrict__ bih1r,
  const float* __restrict__ bhh1r,
  const float* __restrict__ fc1w, const float* __restrict__ fc1b,
  const float* __restrict__ gma,  const float* __restrict__ bta,
  const float* __restrict__ mean, const float* __restrict__ var,
  const float* __restrict__ fc2w, const float* __restrict__ fc2b,
  us* __restrict__ whh0f, us* __restrict__ whh0r,
  us* __restrict__ wih0f, us* __restrict__ wih0r,
  us* __restrict__ wih1,  us* __restrict__ whh1, us* __restrict__ wih1r,
  us* __restrict__ fc1wb, us* __restrict__ fc2wp,
  float* __restrict__ brz0, float* __restrict__ bnih0, float* __restrict__ bnhh0,
  float* __restrict__ brz1, float* __restrict__ bnih1, float* __restrict__ bnhh1,
  float* __restrict__ brz1r,float* __restrict__ bnih1r,float* __restrict__ bnhh1r,
  float* __restrict__ sc2,  float* __restrict__ sh2,   float* __restrict__ fc2bp,
  us* __restrict__ xbp, unsigned* __restrict__ flp)
{
  const int tid = blockIdx.x * blockDim.x + threadIdx.x;
  const int np  = gridDim.x * blockDim.x;
  for (int i = tid; i < 1536*512; i += np){
    whh0f[i] = f2bf(Whh0[i]);
    whh0r[i] = f2bf(Whh0r[i]);
    whh1[i]  = f2bf(Whh1[i]);
  }
  for (int i = tid; i < 1536*32; i += np){
    int n = i >> 5, k = i & 31;
    wih0f[i] = (k < 28) ? f2bf(Wih0[n*28 + k])  : (us)0;
    wih0r[i] = (k < 28) ? f2bf(Wih0r[n*28 + k]) : (us)0;
  }
  for (int i = tid; i < 1536*1024; i += np){
    wih1[i]  = f2bf(Wih1[i]);
    wih1r[i] = f2bf(Wih1r[i]);
  }
  for (int i = tid; i < 256*1024; i += np) fc1wb[i] = f2bf(fc1w[i]);
  for (int i = tid; i < 16*256;   i += np){
    int n = i / 256; fc2wp[i] = (n < 10) ? f2bf(fc2w[i]) : (us)0;
  }
  // x -> bf16, 28 cols padded to 32 (row = (m,t))
  for (int i = tid; i < 4096*28; i += np){
    const float* src = x + (size_t)i * 28;
    us* dst = xbp + (size_t)i * 32;
    #pragma unroll
    for (int k = 0; k < 28; ++k) dst[k] = f2bf(src[k]);
    dst[28] = dst[29] = dst[30] = dst[31] = 0;
  }
  for (int i = tid; i < FL_TOTAL; i += np) flp[i] = 0;  // re-zeroed each run
  for (int i = tid; i < 1024; i += np){
    brz0[i]        = bih0[i]  + bhh0[i];
    brz0[1024 + i] = bih0r[i] + bhh0r[i];
    brz1[i]        = bih1[i]  + bhh1[i];
    brz1r[i]       = bih1r[i] + bhh1r[i];
  }
  for (int i = tid; i < 512; i += np){
    bnih0[i]       = bih0[1024 + i];   bnhh0[i]       = bhh0[1024 + i];
    bnih0[512 + i] = bih0r[1024 + i];  bnhh0[512 + i] = bhh0r[1024 + i];
    bnih1[i]       = bih1[1024 + i];   bnhh1[i]       = bhh1[1024 + i];
    bnih1r[i]      = bih1r[1024 + i];  bnhh1r[i]      = bhh1r[1024 + i];
  }
  for (int i = tid; i < 256; i += np){
    float s = gma[i] * rsqrtf(var[i] + 1e-5f);
    sc2[i] = s;
    sh2[i] = (fc1b[i] - mean[i]) * s + bta[i];
  }
  for (int i = tid; i < 16; i += np) fc2bp[i] = (i < 10) ? fc2b[i] : 0.f;
}

// ---------------- big GEMM: C[sl][m][1536] = A @ B^T (bf16, no bias) ----------------
// m97 structure (verified round 8: 125 -> ~77 µs): 128x128 tile, 256 thr / 4
// waves (wave tile 64x64, acc[4][4]); A and B staged via global_load_lds
// width-16 into linear LDS, double-buffered; one barrier per K-step.
__global__ __launch_bounds__(256) void gemm_kernel(
  const us* __restrict__ s0, long s0m, long s0t, int K0,
  const us* __restrict__ s1, long s1m, long s1t,
  const us* __restrict__ B, int Kw, int nk, int tshift, int nMtiles,
  us* __restrict__ C, long cT)
{
  __shared__ __align__(16) us As[2*128*32];
  __shared__ __align__(16) us Bs[2*128*32];

  const int tid = threadIdx.x, bid = blockIdx.x;
  const int mtile = bid % nMtiles, ntile = bid / nMtiles;
  const int Mbase = mtile * 128, Nbase = ntile * 128;
  const int mask = (1 << tshift) - 1;
  const int ktSplit = K0 >> 5;

  const int w = tid >> 6, lane = tid & 63, ln = lane & 15, lq = lane >> 4;
  const int wm = w >> 1, wn = w & 1;

  const int r0 = tid >> 2, g0 = tid & 3;
  const int R0 = Mbase + r0, R1 = R0 + 64;
  const int m0 = R0 >> tshift, sl0 = R0 & mask;
  const int m1 = R1 >> tshift, sl1 = R1 & mask;
  const us* pA00 = s0 + (size_t)m0*s0m + (long)sl0*s0t + g0*8;   // kt < ktSplit
  const us* pA01 = s1 + (size_t)m0*s1m + (long)sl0*s1t + g0*8;   // kt >= ktSplit
  const us* pA10 = s0 + (size_t)m1*s0m + (long)sl1*s0t + g0*8;
  const us* pA11 = s1 + (size_t)m1*s1m + (long)sl1*s1t + g0*8;
  const us* pB0  = B + (size_t)(Nbase + r0     )*Kw + g0*8;
  const us* pB1  = B + (size_t)(Nbase + r0 + 64)*Kw + g0*8;

  auto stage = [&](int buf, int kt){
    const int kc = kt*32;
    const us* a0; const us* a1;
    if (kt < ktSplit){ a0 = pA00 + kc; a1 = pA10 + kc; }
    else             { a0 = pA01 + (kc - K0); a1 = pA11 + (kc - K0); }
    gload16(a0,       &As[buf +        w*512]);
    gload16(a1,       &As[buf + 2048 + w*512]);
    gload16(pB0 + kc, &Bs[buf +        w*512]);
    gload16(pB1 + kc, &Bs[buf + 2048 + w*512]);
  };

  stage(0, 0);
  __syncthreads();    // compiler emits vmcnt(0) before the barrier

  f4 acc[4][4] = {};

  for (int kt = 0; kt < nk; ++kt){
    const int buf = (kt & 1) * 4096;
    const bool more = (kt + 1) < nk;
    if (more) stage(buf ^ 4096, kt + 1);
    bf8 a0 = ldb(&As[buf + (wm*64 +  0 + ln)*32 + lq*8]);
    bf8 a1 = ldb(&As[buf + (wm*64 + 16 + ln)*32 + lq*8]);
    bf8 a2 = ldb(&As[buf + (wm*64 + 32 + ln)*32 + lq*8]);
    bf8 a3 = ldb(&As[buf + (wm*64 + 48 + ln)*32 + lq*8]);
    bf8 b0 = ldb(&Bs[buf + (wn*64 +  0 + ln)*32 + lq*8]);
    bf8 b1 = ldb(&Bs[buf + (wn*64 + 16 + ln)*32 + lq*8]);
    bf8 b2 = ldb(&Bs[buf + (wn*64 + 32 + ln)*32 + lq*8]);
    bf8 b3 = ldb(&Bs[buf + (wn*64 + 48 + ln)*32 + lq*8]);
    acc[0][0] = mfma(a0, b0, acc[0][0]); acc[0][1] = mfma(a0, b1, acc[0][1]);
    acc[0][2] = mfma(a0, b2, acc[0][2]); acc[0][3] = mfma(a0, b3, acc[0][3]);
    acc[1][0] = mfma(a1, b0, acc[1][0]); acc[1][1] = mfma(a1, b1, acc[1][1]);
    acc[1][2] = mfma(a1, b2, acc[1][2]); acc[1][3] = mfma(a1, b3, acc[1][3]);
    acc[2][0] = mfma(a2, b0, acc[2][0]); acc[2][1] = mfma(a2, b1, acc[2][1]);
    acc[2][2] = mfma(a2, b2, acc[2][2]); acc[2][3] = mfma(a2, b3, acc[2][3]);
    acc[3][0] = mfma(a3, b0, acc[3][0]); acc[3][1] = mfma(a3, b1, acc[3][1]);
    acc[3][2] = mfma(a3, b2, acc[3][2]); acc[3][3] = mfma(a3, b3, acc[3][3]);
    if (more) __syncthreads();   // drains next-buf gloads; guards buf reuse
  }

  #pragma unroll
  for (int mtf = 0; mtf < 4; ++mtf){
    #pragma unroll
    for (int ntf = 0; ntf < 4; ++ntf){
      const int col = Nbase + wn*64 + ntf*16 + ln;
      #pragma unroll
      for (int e = 0; e < 4; ++e){
        const int R = Mbase + wm*64 + mtf*16 + lq*4 + e;
        const int m = R >> tshift, sl = R & mask;
        C[(size_t)sl*cT + (size_t)m*1536 + col] = f2bf(acc[mtf][ntf][e]);
      }
    }
  }
}

// ---------------- persistent GRU scan: nsteps serial steps, Whh pinned in LDS ----
// Round-8 structure (champion, 1750 µs) with ONE change: the inter-block POLL
// moved from end-of-step to just before the h-part of the NEXT step, so the
// next step's h-independent work (gxv hoist / x-slab staging + x-MFMA) hides
// group skew. Publish (monotone flag = s+1) stays at end of step after the
// store-drain barrier; chunk-first steps (s==s0) skip the poll (kernel-launch
// serialization guarantees h(s0-1) is complete). Watchdogged poll.
template<int USE_X>
__global__ __launch_bounds__(512) void gru_coop_kernel(
  const us* __restrict__ W, const us* __restrict__ Wx,
  const us* __restrict__ xb, const us* __restrict__ gxAll,
  us* __restrict__ hPP, float* __restrict__ hF,
  us* __restrict__ y, long ymstride, int ymode,
  const float* __restrict__ brz, const float* __restrict__ bni,
  const float* __restrict__ bnh,
  int s0, int nsteps, int rev, unsigned* __restrict__ flags)
{
  __shared__ us Ws[96*520];
  __shared__ us Wxs[96*40];
  __shared__ us As[2*256*40];

  const int tid = threadIdx.x, bid = blockIdx.x;
  const int hcb = bid >> 4, nm = bid & 15;
  const size_t Mbase = (size_t)nm * 256;
  const int hcBase = hcb * 32;
  const int w = tid >> 6, lane = tid & 63, ln = lane & 15, lq = lane >> 4;
  unsigned* const fl = flags + nm * FL_GRP;

  #pragma unroll
  for (int i = 0; i < 12; ++i){
    const int q = tid + i*512;
    const int rl = q >> 6, seg = q & 63;
    const int grow = (rl >> 5)*512 + hcBase + (rl & 31);
    *reinterpret_cast<uint4*>(&Ws[rl*520 + seg*8]) =
      *reinterpret_cast<const uint4*>(&W[(size_t)grow*512 + seg*8]);
  }
  if (USE_X && tid < 384){
    const int rl = tid >> 2, seg = tid & 3;
    const int grow = (rl >> 5)*512 + hcBase + (rl & 31);
    *reinterpret_cast<uint4*>(&Wxs[rl*40 + seg*8]) =
      *reinterpret_cast<const uint4*>(&Wx[(size_t)grow*32 + seg*8]);
  }

  auto stA = [&](int buf, int q, uint4 v){
    const int row = q >> 2, grp = q & 3;
    *reinterpret_cast<uint4*>(&As[buf + row*40 + grp*8]) = v;
  };

  float hreg[2][2][4];
  #pragma unroll
  for (int nt = 0; nt < 2; ++nt)
    #pragma unroll
    for (int mt = 0; mt < 2; ++mt)
      #pragma unroll
      for (int e = 0; e < 4; ++e) hreg[nt][mt][e] = 0.f;
  if (s0 > 0){
    #pragma unroll
    for (int nt = 0; nt < 2; ++nt){
      const int ch = hcBase + nt*16 + ln;
      #pragma unroll
      for (int mt = 0; mt < 2; ++mt)
        #pragma unroll
        for (int e = 0; e < 4; ++e){
          const size_t m = Mbase + w*32 + mt*16 + lq*4 + e;
          hreg[nt][mt][e] = hF[m*512 + ch];
        }
    }
  }

  for (int s = s0; s < s0 + nsteps; ++s){
    const int t = rev ? 27 - s : s;
    const bool first = (s == 0);
    const bool last  = (s == s0 + nsteps - 1);

    const us* hin; long hinm;
    us* hOut = nullptr;
    if (ymode == 1){ hin = y + (size_t)(rev ? t + 1 : t - 1) * 512; hinm = ymstride; }
    else if (ymode == 2){ hin = y + (size_t)((s - 1) & 3) * 512; hinm = ymstride; }
    else {
      hin  = hPP + (size_t)(s & 1) * PPH; hinm = 512;
      hOut = hPP + (size_t)((s & 1) ^ 1) * PPH;
    }

    auto ldH = [&](int kt, int q) -> uint4 {
      const int row = q >> 2, grp = q & 3;
      return *reinterpret_cast<const uint4*>(&hin[(Mbase + row)*hinm + kt*32 + grp*8]);
    };

    f4 acc[3][2][2] = {};
    f4 accNX[2][2] = {};

    // ---- h-independent work first: gxv hoist / x staging (overlaps the poll)
    us gxv[12][4];
    if (!USE_X){
      const us* gx = gxAll + (size_t)(s - s0) * PLANE;
      #pragma unroll
      for (int nt = 0; nt < 2; ++nt){
        const int ch = hcBase + nt*16 + ln;
        #pragma unroll
        for (int mt = 0; mt < 2; ++mt){
          #pragma unroll
          for (int e = 0; e < 4; ++e){
            const size_t m = Mbase + w*32 + mt*16 + lq*4 + e;
            const us* gxr = gx + m*1536;
            gxv[0 + nt*2 + mt][e] = gxr[ch];
            gxv[4 + nt*2 + mt][e] = gxr[512 + ch];
            gxv[8 + nt*2 + mt][e] = gxr[1024 + ch];
          }
        }
      }
    }
    if (USE_X){
      #pragma unroll
      for (int i = 0; i < 2; ++i){
        const int q = tid + i*512;
        const int row = q >> 2, grp = q & 3;
        uint4 v = *reinterpret_cast<const uint4*>(
          &xb[((Mbase + row)*28 + (size_t)t)*32 + grp*8]);
        stA(0, q, v);
      }
    }
    __syncthreads();   // x slab visible (also orders W-slab load on s0 iter)

    // ---- x-projection K-tile (K=32, Wxs pinned) — still before the poll
    if (USE_X){
      bf8 a0 = ldb(&As[(w*32 +  0 + ln)*40 + lq*8]);
      bf8 a1 = ldb(&As[(w*32 + 16 + ln)*40 + lq*8]);
      #pragma unroll
      for (int g = 0; g < 3; ++g){
        #pragma unroll
        for (int nt = 0; nt < 2; ++nt){
          bf8 b = ldb(&Wxs[(g*32 + nt*16 + ln)*40 + lq*8]);
          if (g == 2){
            accNX[nt][0] = mfma(a0, b, accNX[nt][0]);
            accNX[nt][1] = mfma(a1, b, accNX[nt][1]);
          } else {
            acc[g][nt][0] = mfma(a0, b, acc[g][nt][0]);
            acc[g][nt][1] = mfma(a1, b, acc[g][nt][1]);
          }
        }
      }
    }

    // ---- NOW wait for the group to have finished step s-1 (skip at chunk start)
    if (s > s0){
      if (tid < 16){
        const unsigned tgt = (unsigned)s;
        int guard = 0;
        while (__hip_atomic_load(fl + tid, __ATOMIC_RELAXED,
                                 __HIP_MEMORY_SCOPE_AGENT) < tgt){
          __builtin_amdgcn_s_sleep(1);
          if (++guard > (1 << 18)) break;   // watchdog: never hang the queue
        }
      }
      __syncthreads();
    }

    // ---- h @ Whh^T, 16 K-tiles, A double-buffered (round-8 loop, unchanged)
    if (!first){
      const int B0 = USE_X ? 10240 : 0;
      stA(B0, tid, ldH(0, tid)); stA(B0, tid + 512, ldH(0, tid + 512));
      uint4 s1a = ldH(1, tid), s1b = ldH(1, tid + 512);
      uint4 s2a = ldH(2, tid), s2b = ldH(2, tid + 512);
      __syncthreads();

      for (int kt = 0; kt < 16; ++kt){
        const int buf = B0 ^ ((kt & 1) * 10240);
        bf8 a0 = ldb(&As[buf + (w*32 +  0 + ln)*40 + lq*8]);
        bf8 a1 = ldb(&As[buf + (w*32 + 16 + ln)*40 + lq*8]);
        const int kc = kt*32 + lq*8;
        #pragma unroll
        for (int g = 0; g < 3; ++g){
          #pragma unroll
          for (int nt = 0; nt < 2; ++nt){
            bf8 b = ldb(&Ws[(g*32 + nt*16 + ln)*520 + kc]);
            acc[g][nt][0] = mfma(a0, b, acc[g][nt][0]);
            acc[g][nt][1] = mfma(a1, b, acc[g][nt][1]);
          }
        }
        if (kt < 15){
          stA(buf ^ 10240, tid, s1a); stA(buf ^ 10240, tid + 512, s1b);
          s1a = s2a; s1b = s2b;
          if (kt + 3 < 16){ s2a = ldH(kt + 3, tid); s2b = ldH(kt + 3, tid + 512); }
          __syncthreads();
        }
      }
    }

    // ---- gate epilogue (hprev from registers; h plane write = y slice)
    #pragma unroll
    for (int nt = 0; nt < 2; ++nt){
      const int ch = hcBase + nt*16 + ln;
      const float br = brz[ch], bz = brz[512 + ch], bi = bni[ch], bh = bnh[ch];
      #pragma unroll
      for (int mt = 0; mt < 2; ++mt){
        #pragma unroll
        for (int e = 0; e < 4; ++e){
          const size_t m = Mbase + w*32 + mt*16 + lq*4 + e;
          float rr = acc[0][nt][mt][e] + br;
          float zz = acc[1][nt][mt][e] + bz;
          float xr = accNX[nt][mt][e];
          if (!USE_X){
            rr += bf2f(gxv[0 + nt*2 + mt][e]);
            zz += bf2f(gxv[4 + nt*2 + mt][e]);
            xr += bf2f(gxv[8 + nt*2 + mt][e]);
          }
          float r = sigm(rr);
          float z = sigm(zz);
          float n = tanhf(xr + bi + r*(acc[2][nt][mt][e] + bh));
          float hprev = first ? 0.f : hreg[nt][mt][e];
          float h = (1.f - z)*n + z*hprev;
          hreg[nt][mt][e] = h;
          if (last && hF) hF[m*512 + ch] = h;
          us hb = f2bf(h);
          if (ymode == 0)      hOut[m*512 + ch] = hb;
          else if (ymode == 1) y[m*ymstride + (size_t)t*512 + ch] = hb;
          else                 y[m*ymstride + (size_t)(s - s0)*512 + ch] = hb;
        }
      }
    }

    // ---- publish only (poll happens at the top of the next step)
    if (!last){
      __syncthreads();   // every wave: vmcnt(0)+barrier -> all stores in XCD L2
      if (tid == 0)
        __hip_atomic_store(fl + hcb, (unsigned)(s + 1),
                           __ATOMIC_RELAXED, __HIP_MEMORY_SCOPE_AGENT);
    }
  }
}

// ---------------- l1 backward single step: elementwise gates from gxb (h=0) ----
__global__ void gate1b_kernel(
  const us* __restrict__ gxb, const float* __restrict__ brz,
  const float* __restrict__ bni, const float* __restrict__ bnh,
  us* __restrict__ h1b)
{
  const int i = blockIdx.x * blockDim.x + threadIdx.x;
  if (i >= 4096*512) return;
  const int m = i >> 9, ch = i & 511;
  const us* g = gxb + (size_t)m*1536;
  float r = sigm(bf2f(g[ch]) + brz[ch]);
  float z = sigm(bf2f(g[512 + ch]) + brz[512 + ch]);
  float n = tanhf(bf2f(g[1024 + ch]) + bni[ch] + r*bnh[ch]);
  h1b[i] = f2bf((1.f - z)*n);
}

// ---------------- head: [h1f|h1b] -> fc1 -> bn/relu -> fc2 -> log_softmax ----
__global__ __launch_bounds__(512) void head_kernel(
  const us* __restrict__ h1f, const us* __restrict__ h1b,
  const us* __restrict__ fc1w, const us* __restrict__ fc2wp,
  const float* __restrict__ sc2, const float* __restrict__ sh2,
  const float* __restrict__ fc2b, float* __restrict__ out)
{
  constexpr int APS = 1048;
  __shared__ us As[32 * APS];
  __shared__ us actS[32 * 264];
  __shared__ float lg[32 * 16];
  const int tid = threadIdx.x;
  const size_t row0 = (size_t)blockIdx.x * 32;
  const int w = tid >> 6, lane = tid & 63, ln = lane & 15, lq = lane >> 4;

  for (int i = tid; i < 32*128; i += 512){
    int r = i >> 7, g = i & 127, col = g*8;
    uint4 v = (col < 512)
      ? *reinterpret_cast<const uint4*>(h1f + (row0 + r)*512 + col)
      : *reinterpret_cast<const uint4*>(h1b + (row0 + r)*512 + (col - 512));
    *reinterpret_cast<uint4*>(&As[r*APS + col]) = v;
  }
  __syncthreads();

  {
    f4 acc[2][2] = {};
    for (int kt = 0; kt < 32; ++kt){
      const int kc = kt*32 + lq*8;
      bf8 a0 = ldb(&As[ln*APS + kc]);
      bf8 a1 = ldb(&As[(16 + ln)*APS + kc]);
      #pragma unroll
      for (int nt = 0; nt < 2; ++nt){
        const int col = w*32 + nt*16 + ln;
        bf8 b = ldb(&fc1w[(size_t)col*1024 + kc]);
        acc[0][nt] = mfma(a0, b, acc[0][nt]);
        acc[1][nt] = mfma(a1, b, acc[1][nt]);
      }
    }
    #pragma unroll
    for (int nt = 0; nt < 2; ++nt){
      const int col = w*32 + nt*16 + ln;
      const float sc = sc2[col], sh = sh2[col];
      #pragma unroll
      for (int mt = 0; mt < 2; ++mt)
        #pragma unroll
        for (int e = 0; e < 4; ++e){
          float v = fmaxf(acc[mt][nt][e]*sc + sh, 0.f);
          actS[(mt*16 + lq*4 + e)*264 + col] = f2bf(v);
        }
    }
    __syncthreads();
  }

  if (w == 0){
    f4 acc[2] = {};
    for (int kt = 0; kt < 8; ++kt){
      const int kc = kt*32 + lq*8;
      bf8 a0 = ldb(&actS[ln*264 + kc]);
      bf8 a1 = ldb(&actS[(16 + ln)*264 + kc]);
      bf8 b  = ldb(&fc2wp[ln*256 + kc]);
      acc[0] = mfma(a0, b, acc[0]);
      acc[1] = mfma(a1, b, acc[1]);
    }
    const float bb = fc2b[ln];
    #pragma unroll
    for (int mt = 0; mt < 2; ++mt)
      #pragma unroll
      for (int e = 0; e < 4; ++e)
        lg[(mt*16 + lq*4 + e)*16 + ln] = acc[mt][e] + bb;
  }
  __syncthreads();
  if (tid < 32){
    const int r = tid;
    float mx = -1e30f;
    for (int cc = 0; cc < 10; ++cc) mx = fmaxf(mx, lg[r*16 + cc]);
    float sum = 0.f;
    for (int cc = 0; cc < 10; ++cc) sum += __expf(lg[r*16 + cc] - mx);
    const float lse = mx + logf(sum);
    for (int cc = 0; cc < 10; ++cc)
      out[(row0 + r)*10 + cc] = lg[r*16 + cc] - lse;
  }
}

// ---------------- launch ----------------
extern "C" void kernel_launch(void* const* d_in, const int* in_sizes, int n_in,
                              void* d_out, int out_size, void* d_ws, size_t ws_size,
                              hipStream_t stream)
{
  (void)in_sizes; (void)n_in; (void)out_size; (void)ws_size;
  char* ws = (char*)d_ws;
  auto US = [&](size_t off){ return (us*)(ws + off); };
  auto FP = [&](size_t off){ return (float*)(ws + off); };

  const float* x      = (const float*)d_in[0];
  const float* Wih0   = (const float*)d_in[1];
  const float* Whh0   = (const float*)d_in[2];
  const float* bih0   = (const float*)d_in[3];
  const float* bhh0   = (const float*)d_in[4];
  const float* Wih0r  = (const float*)d_in[5];
  const float* Whh0r  = (const float*)d_in[6];
  const float* bih0r  = (const float*)d_in[7];
  const float* bhh0r  = (const float*)d_in[8];
  const float* Wih1   = (const float*)d_in[9];
  const float* Whh1   = (const float*)d_in[10];
  const float* bih1   = (const float*)d_in[11];
  const float* bhh1   = (const float*)d_in[12];
  const float* Wih1r  = (const float*)d_in[13];
  // d_in[14] (W_hh_l1r) unused: backward layer-1 runs exactly one step from h=0.
  const float* bih1r  = (const float*)d_in[15];
  const float* bhh1r  = (const float*)d_in[16];
  const float* fc1w   = (const float*)d_in[17];
  const float* fc1b   = (const float*)d_in[18];
  const float* gma    = (const float*)d_in[19];
  const float* bta    = (const float*)d_in[20];
  const float* mean   = (const float*)d_in[21];
  const float* var    = (const float*)d_in[22];
  const float* fc2w   = (const float*)d_in[23];
  const float* fc2b   = (const float*)d_in[24];

  prep_kernel<<<512, 256, 0, stream>>>(
    x, Wih0, Whh0, bih0, bhh0, Wih0r, Whh0r, bih0r, bhh0r,
    Wih1, Whh1, bih1, bhh1, Wih1r, bih1r, bhh1r,
    fc1w, fc1b, gma, bta, mean, var, fc2w, fc2b,
    US(OFF_WHH0F), US(OFF_WHH0R), US(OFF_WIH0F), US(OFF_WIH0R),
    US(OFF_WIH1), US(OFF_WHH1), US(OFF_WIH1R), US(OFF_FC1W), US(OFF_FC2W),
    FP(OFF_BRZ0), FP(OFF_BNIH0), FP(OFF_BNHH0),
    FP(OFF_BRZ1), FP(OFF_BNIH1), FP(OFF_BNHH1),
    FP(OFF_BRZ1R), FP(OFF_BNIH1R), FP(OFF_BNHH1R),
    FP(OFF_SC2), FP(OFF_SH2), FP(OFF_FC2B),
    US(OFF_XB), (unsigned*)(ws + OFF_BAR));

  us* y0b  = US(OFF_Y0B);
  us* y0fc = US(OFF_Y0FC);
  us* gx   = US(OFF_GX);
  us* h1bf = US(OFF_H1BF);
  us* xb   = US(OFF_XB);
  unsigned* fl = (unsigned*)(ws + OFF_BAR);

  // ---- phase A: layer-0 backward — one persistent launch; h lives in y0b slices
  gru_coop_kernel<1><<<256, 512, 0, stream>>>(
    US(OFF_WHH0R), US(OFF_WIH0R), xb, nullptr,
    nullptr, nullptr, y0b, 28ll*512, 1,
    FP(OFF_BRZ0) + 1024, FP(OFF_BNIH0) + 512, FP(OFF_BNHH0) + 512,
    0, 28, 1, fl + 0*FL_SLOT);

  // ---- phase B: l0f chunk (h in y0fc ring) + gx1 gemm + l1f chunk ----
  for (int c = 0; c < 7; ++c){
    const int t0 = 4*c;
    gru_coop_kernel<1><<<256, 512, 0, stream>>>(
      US(OFF_WHH0F), US(OFF_WIH0F), xb, nullptr,
      nullptr, FP(OFF_H0F32), y0fc, 4ll*512, 2,
      FP(OFF_BRZ0), FP(OFF_BNIH0), FP(OFF_BNHH0),
      t0, 4, 0, fl + 1*FL_SLOT);
    // gx1[sl] = [y0fc[:,sl,:] | y0b[:,t0+sl,:]] @ Wih1^T  (K=1024, nk=32)
    gemm_kernel<<<128*12, 256, 0, stream>>>(
      y0fc, 4ll*512, 512, 512,
      y0b + t0*512, 28ll*512, 512,
      US(OFF_WIH1), 1024, 32, 2, 128, gx, PLANE);
    gru_coop_kernel<0><<<256, 512, 0, stream>>>(
      US(OFF_WHH1), nullptr, nullptr, gx,
      h1bf, FP(OFF_H1F32), nullptr, 0, 0,
      FP(OFF_BRZ1), FP(OFF_BNIH1), FP(OFF_BNHH1),
      t0, 4, 0, fl + 2*FL_SLOT);
  }

  // ---- layer-1 backward: gxb = [h0f_27 | y0b_27] @ Wih1r^T, then gates (h=0) ----
  // h0f final state (t=27) = y0fc slice 3 after the last l0f chunk.
  gemm_kernel<<<32*12, 256, 0, stream>>>(
    y0fc + 3*512, 4ll*512, 0, 512,
    y0b + 27*512, 28ll*512, 0,
    US(OFF_WIH1R), 1024, 32, 0, 32, gx, 0);
  gate1b_kernel<<<8192, 256, 0, stream>>>(
    gx, FP(OFF_BRZ1R), FP(OFF_BNIH1R), FP(OFF_BNHH1R), US(OFF_H1B));

  // ---- head (h1f final is pp buffer 0 after 28 steps) ----
  head_kernel<<<128, 512, 0, stream>>>(
    h1bf, US(OFF_H1B), US(OFF_FC1W), US(OFF_FC2W),
    FP(OFF_SC2), FP(OFF_SH2), FP(OFF_FC2B), (float*)d_out);
}

// Round 14
// 1581.864 us; speedup vs baseline: 1.1600x; 1.0680x over previous
//
#include <hip/hip_runtime.h>

#define DEV __device__ __forceinline__
typedef unsigned short us;
typedef __bf16 bf8 __attribute__((ext_vector_type(8)));
typedef float  f4  __attribute__((ext_vector_type(4)));

DEV us f2bf(float f){
  unsigned int u = __builtin_bit_cast(unsigned int, f);
  u = u + 0x7fffu + ((u >> 16) & 1u);
  return (us)(u >> 16);
}
DEV float bf2f(us u){ unsigned int v = ((unsigned int)u) << 16; return __builtin_bit_cast(float, v); }

// fast gate math: v_exp_f32 + v_rcp_f32 (err ~1e-6 << bf16 rounding already in absmax)
DEV float sigm(float x){
  float e = __builtin_amdgcn_exp2f(x * -1.44269504088896340736f);   // exp(-x)
  return __builtin_amdgcn_rcpf(1.f + e);
}
DEV float tanh_fast(float x){
  float e = __builtin_amdgcn_exp2f(x * 2.88539008177792681472f);    // exp(2x)
  return 1.f - 2.f * __builtin_amdgcn_rcpf(e + 1.f);
}
DEV bf8 ldb(const us* p){ return *reinterpret_cast<const bf8*>(p); }
DEV f4 mfma(bf8 a, bf8 b, f4 c){ return __builtin_amdgcn_mfma_f32_16x16x32_bf16(a, b, c, 0, 0, 0); }

// async global->LDS, 16B per lane: lds dest = wave-uniform base + lane*16,
// global src = per-lane address. (m97 technique: +67% on the GEMM ladder)
DEV void gload16(const us* g, us* l){
  __builtin_amdgcn_global_load_lds(
    (const __attribute__((address_space(1))) unsigned int*)g,
    (__attribute__((address_space(3))) unsigned int*)l, 16, 0, 0);
}

// ---------------- workspace layout (bytes) — total ~236 MB (<246.75 proven safe)
constexpr size_t OFF_WHH0F  = 0;                             // [1536][512] bf16
constexpr size_t OFF_WHH0R  = OFF_WHH0F + 1536ull*512*2;
constexpr size_t OFF_WIH0F  = OFF_WHH0R + 1536ull*512*2;     // [1536][32] bf16
constexpr size_t OFF_WIH0R  = OFF_WIH0F + 1536ull*32*2;
constexpr size_t OFF_WIH1   = OFF_WIH0R + 1536ull*32*2;      // [1536][1024] bf16
constexpr size_t OFF_WHH1   = OFF_WIH1  + 1536ull*1024*2;    // [1536][512] bf16
constexpr size_t OFF_WIH1R  = OFF_WHH1  + 1536ull*512*2;     // [1536][1024] bf16
constexpr size_t OFF_FC1W   = OFF_WIH1R + 1536ull*1024*2;    // [256][1024] bf16
constexpr size_t OFF_FC2W   = OFF_FC1W  + 256ull*1024*2;     // [16][256] bf16
constexpr size_t OFF_BRZ0   = OFF_FC2W  + 16ull*256*2;       // [2][1024] f32
constexpr size_t OFF_BNIH0  = OFF_BRZ0  + 2*1024*4;          // [2][512]
constexpr size_t OFF_BNHH0  = OFF_BNIH0 + 2*512*4;           // [2][512]
constexpr size_t OFF_BRZ1   = OFF_BNHH0 + 2*512*4;           // [1024]
constexpr size_t OFF_BNIH1  = OFF_BRZ1  + 1024*4;            // [512]
constexpr size_t OFF_BNHH1  = OFF_BNIH1 + 512*4;             // [512]
constexpr size_t OFF_BRZ1R  = OFF_BNHH1 + 512*4;             // [1024]
constexpr size_t OFF_BNIH1R = OFF_BRZ1R + 1024*4;            // [512]
constexpr size_t OFF_BNHH1R = OFF_BNIH1R+ 512*4;             // [512]
constexpr size_t OFF_SC2    = OFF_BNHH1R+ 512*4;             // [256]
constexpr size_t OFF_SH2    = OFF_SC2   + 256*4;             // [256]
constexpr size_t OFF_FC2B   = OFF_SH2   + 256*4;             // [16]
constexpr size_t OFF_Y0B    = OFF_FC2B  + 64;                // [4096][28][512] bf16 (= h0b planes)
constexpr size_t OFF_Y0FC   = OFF_Y0B   + 4096ull*28*512*2;  // [4096][4][512] bf16 (= h0f planes)
constexpr size_t OFF_GX     = OFF_Y0FC  + 4096ull*4*512*2;   // [4][4096][1536] bf16
constexpr size_t OFF_H0BF   = OFF_GX    + 4ull*4096*1536*2;  // (unused, kept for layout stability)
constexpr size_t OFF_H0F32  = OFF_H0BF  + 2ull*4096*512*2;   // [4096][512] f32 (l0f cross-launch)
constexpr size_t OFF_H1BF   = OFF_H0F32 + 4096ull*512*4;     // [2pp][4096][512] bf16 (l1f)
constexpr size_t OFF_H1F32  = OFF_H1BF  + 2ull*4096*512*2;   // [4096][512] f32 (l1f cross-launch)
constexpr size_t OFF_H1B    = OFF_H1F32 + 4096ull*512*4;     // [4096][512] bf16
constexpr size_t OFF_XB     = OFF_H1B   + 4096ull*512*2;     // [4096][28][32] bf16 (x pad)
constexpr size_t OFF_BAR    = OFF_XB    + 4096ull*28*32*2;   // flag slots

// flags: slot = 16 groups x 64 u32 (group line padded to 256B). 3 slots used
// (A / l0f / l1f); flags are MONOTONE within a run -> rocprof replays safe.
constexpr int FL_GRP  = 64;            // u32 per group
constexpr int FL_SLOT = 16*FL_GRP;     // u32 per slot
constexpr int FL_TOTAL= 16*FL_SLOT;    // zero generous region

constexpr long PPH   = 4096ll*512;     // h ping-pong plane (elems)
constexpr long PLANE = 4096ll*1536;    // gx per-t plane (elems)

// ---------------- K0: weight/bias prep + x->bf16 pad + flag zero ----------------
__global__ void prep_kernel(
  const float* __restrict__ x,
  const float* __restrict__ Wih0, const float* __restrict__ Whh0,
  const float* __restrict__ bih0, const float* __restrict__ bhh0,
  const float* __restrict__ Wih0r,const float* __restrict__ Whh0r,
  const float* __restrict__ bih0r,const float* __restrict__ bhh0r,
  const float* __restrict__ Wih1, const float* __restrict__ Whh1,
  const float* __restrict__ bih1, const float* __restrict__ bhh1,
  const float* __restrict__ Wih1r,const float* __restrict__ bih1r,
  const float* __restrict__ bhh1r,
  const float* __restrict__ fc1w, const float* __restrict__ fc1b,
  const float* __restrict__ gma,  const float* __restrict__ bta,
  const float* __restrict__ mean, const float* __restrict__ var,
  const float* __restrict__ fc2w, const float* __restrict__ fc2b,
  us* __restrict__ whh0f, us* __restrict__ whh0r,
  us* __restrict__ wih0f, us* __restrict__ wih0r,
  us* __restrict__ wih1,  us* __restrict__ whh1, us* __restrict__ wih1r,
  us* __restrict__ fc1wb, us* __restrict__ fc2wp,
  float* __restrict__ brz0, float* __restrict__ bnih0, float* __restrict__ bnhh0,
  float* __restrict__ brz1, float* __restrict__ bnih1, float* __restrict__ bnhh1,
  float* __restrict__ brz1r,float* __restrict__ bnih1r,float* __restrict__ bnhh1r,
  float* __restrict__ sc2,  float* __restrict__ sh2,   float* __restrict__ fc2bp,
  us* __restrict__ xbp, unsigned* __restrict__ flp)
{
  const int tid = blockIdx.x * blockDim.x + threadIdx.x;
  const int np  = gridDim.x * blockDim.x;
  for (int i = tid; i < 1536*512; i += np){
    whh0f[i] = f2bf(Whh0[i]);
    whh0r[i] = f2bf(Whh0r[i]);
    whh1[i]  = f2bf(Whh1[i]);
  }
  for (int i = tid; i < 1536*32; i += np){
    int n = i >> 5, k = i & 31;
    wih0f[i] = (k < 28) ? f2bf(Wih0[n*28 + k])  : (us)0;
    wih0r[i] = (k < 28) ? f2bf(Wih0r[n*28 + k]) : (us)0;
  }
  for (int i = tid; i < 1536*1024; i += np){
    wih1[i]  = f2bf(Wih1[i]);
    wih1r[i] = f2bf(Wih1r[i]);
  }
  for (int i = tid; i < 256*1024; i += np) fc1wb[i] = f2bf(fc1w[i]);
  for (int i = tid; i < 16*256;   i += np){
    int n = i / 256; fc2wp[i] = (n < 10) ? f2bf(fc2w[i]) : (us)0;
  }
  // x -> bf16, 28 cols padded to 32 (row = (m,t))
  for (int i = tid; i < 4096*28; i += np){
    const float* src = x + (size_t)i * 28;
    us* dst = xbp + (size_t)i * 32;
    #pragma unroll
    for (int k = 0; k < 28; ++k) dst[k] = f2bf(src[k]);
    dst[28] = dst[29] = dst[30] = dst[31] = 0;
  }
  for (int i = tid; i < FL_TOTAL; i += np) flp[i] = 0;  // re-zeroed each run
  for (int i = tid; i < 1024; i += np){
    brz0[i]        = bih0[i]  + bhh0[i];
    brz0[1024 + i] = bih0r[i] + bhh0r[i];
    brz1[i]        = bih1[i]  + bhh1[i];
    brz1r[i]       = bih1r[i] + bhh1r[i];
  }
  for (int i = tid; i < 512; i += np){
    bnih0[i]       = bih0[1024 + i];   bnhh0[i]       = bhh0[1024 + i];
    bnih0[512 + i] = bih0r[1024 + i];  bnhh0[512 + i] = bhh0r[1024 + i];
    bnih1[i]       = bih1[1024 + i];   bnhh1[i]       = bhh1[1024 + i];
    bnih1r[i]      = bih1r[1024 + i];  bnhh1r[i]      = bhh1r[1024 + i];
  }
  for (int i = tid; i < 256; i += np){
    float s = gma[i] * rsqrtf(var[i] + 1e-5f);
    sc2[i] = s;
    sh2[i] = (fc1b[i] - mean[i]) * s + bta[i];
  }
  for (int i = tid; i < 16; i += np) fc2bp[i] = (i < 10) ? fc2b[i] : 0.f;
}

// ---------------- big GEMM: C[sl][m][1536] = A @ B^T (bf16, no bias) ----------------
// m97 structure (verified round 8: 125 -> ~77 µs): 128x128 tile, 256 thr / 4
// waves (wave tile 64x64, acc[4][4]); A and B staged via global_load_lds
// width-16 into linear LDS, double-buffered; one barrier per K-step.
__global__ __launch_bounds__(256) void gemm_kernel(
  const us* __restrict__ s0, long s0m, long s0t, int K0,
  const us* __restrict__ s1, long s1m, long s1t,
  const us* __restrict__ B, int Kw, int nk, int tshift, int nMtiles,
  us* __restrict__ C, long cT)
{
  __shared__ __align__(16) us As[2*128*32];
  __shared__ __align__(16) us Bs[2*128*32];

  const int tid = threadIdx.x, bid = blockIdx.x;
  const int mtile = bid % nMtiles, ntile = bid / nMtiles;
  const int Mbase = mtile * 128, Nbase = ntile * 128;
  const int mask = (1 << tshift) - 1;
  const int ktSplit = K0 >> 5;

  const int w = tid >> 6, lane = tid & 63, ln = lane & 15, lq = lane >> 4;
  const int wm = w >> 1, wn = w & 1;

  const int r0 = tid >> 2, g0 = tid & 3;
  const int R0 = Mbase + r0, R1 = R0 + 64;
  const int m0 = R0 >> tshift, sl0 = R0 & mask;
  const int m1 = R1 >> tshift, sl1 = R1 & mask;
  const us* pA00 = s0 + (size_t)m0*s0m + (long)sl0*s0t + g0*8;   // kt < ktSplit
  const us* pA01 = s1 + (size_t)m0*s1m + (long)sl0*s1t + g0*8;   // kt >= ktSplit
  const us* pA10 = s0 + (size_t)m1*s0m + (long)sl1*s0t + g0*8;
  const us* pA11 = s1 + (size_t)m1*s1m + (long)sl1*s1t + g0*8;
  const us* pB0  = B + (size_t)(Nbase + r0     )*Kw + g0*8;
  const us* pB1  = B + (size_t)(Nbase + r0 + 64)*Kw + g0*8;

  auto stage = [&](int buf, int kt){
    const int kc = kt*32;
    const us* a0; const us* a1;
    if (kt < ktSplit){ a0 = pA00 + kc; a1 = pA10 + kc; }
    else             { a0 = pA01 + (kc - K0); a1 = pA11 + (kc - K0); }
    gload16(a0,       &As[buf +        w*512]);
    gload16(a1,       &As[buf + 2048 + w*512]);
    gload16(pB0 + kc, &Bs[buf +        w*512]);
    gload16(pB1 + kc, &Bs[buf + 2048 + w*512]);
  };

  stage(0, 0);
  __syncthreads();    // compiler emits vmcnt(0) before the barrier

  f4 acc[4][4] = {};

  for (int kt = 0; kt < nk; ++kt){
    const int buf = (kt & 1) * 4096;
    const bool more = (kt + 1) < nk;
    if (more) stage(buf ^ 4096, kt + 1);
    bf8 a0 = ldb(&As[buf + (wm*64 +  0 + ln)*32 + lq*8]);
    bf8 a1 = ldb(&As[buf + (wm*64 + 16 + ln)*32 + lq*8]);
    bf8 a2 = ldb(&As[buf + (wm*64 + 32 + ln)*32 + lq*8]);
    bf8 a3 = ldb(&As[buf + (wm*64 + 48 + ln)*32 + lq*8]);
    bf8 b0 = ldb(&Bs[buf + (wn*64 +  0 + ln)*32 + lq*8]);
    bf8 b1 = ldb(&Bs[buf + (wn*64 + 16 + ln)*32 + lq*8]);
    bf8 b2 = ldb(&Bs[buf + (wn*64 + 32 + ln)*32 + lq*8]);
    bf8 b3 = ldb(&Bs[buf + (wn*64 + 48 + ln)*32 + lq*8]);
    acc[0][0] = mfma(a0, b0, acc[0][0]); acc[0][1] = mfma(a0, b1, acc[0][1]);
    acc[0][2] = mfma(a0, b2, acc[0][2]); acc[0][3] = mfma(a0, b3, acc[0][3]);
    acc[1][0] = mfma(a1, b0, acc[1][0]); acc[1][1] = mfma(a1, b1, acc[1][1]);
    acc[1][2] = mfma(a1, b2, acc[1][2]); acc[1][3] = mfma(a1, b3, acc[1][3]);
    acc[2][0] = mfma(a2, b0, acc[2][0]); acc[2][1] = mfma(a2, b1, acc[2][1]);
    acc[2][2] = mfma(a2, b2, acc[2][2]); acc[2][3] = mfma(a2, b3, acc[2][3]);
    acc[3][0] = mfma(a3, b0, acc[3][0]); acc[3][1] = mfma(a3, b1, acc[3][1]);
    acc[3][2] = mfma(a3, b2, acc[3][2]); acc[3][3] = mfma(a3, b3, acc[3][3]);
    if (more) __syncthreads();   // drains next-buf gloads; guards buf reuse
  }

  #pragma unroll
  for (int mtf = 0; mtf < 4; ++mtf){
    #pragma unroll
    for (int ntf = 0; ntf < 4; ++ntf){
      const int col = Nbase + wn*64 + ntf*16 + ln;
      #pragma unroll
      for (int e = 0; e < 4; ++e){
        const int R = Mbase + wm*64 + mtf*16 + lq*4 + e;
        const int m = R >> tshift, sl = R & mask;
        C[(size_t)sl*cT + (size_t)m*1536 + col] = f2bf(acc[mtf][ntf][e]);
      }
    }
  }
}

// ---------------- persistent GRU scan: nsteps serial steps, Whh pinned in LDS ----
// Round-13 structure (champion, 1689 µs): poll moved before the h-part so the
// next step's h-independent work (gxv hoist / x staging + x-MFMA) hides group
// skew; publish (monotone flag = s+1) after the store-drain barrier. THIS
// round: fast gate math only (v_exp/v_rcp tanh+sigmoid).
template<int USE_X>
__global__ __launch_bounds__(512) void gru_coop_kernel(
  const us* __restrict__ W, const us* __restrict__ Wx,
  const us* __restrict__ xb, const us* __restrict__ gxAll,
  us* __restrict__ hPP, float* __restrict__ hF,
  us* __restrict__ y, long ymstride, int ymode,
  const float* __restrict__ brz, const float* __restrict__ bni,
  const float* __restrict__ bnh,
  int s0, int nsteps, int rev, unsigned* __restrict__ flags)
{
  __shared__ us Ws[96*520];
  __shared__ us Wxs[96*40];
  __shared__ us As[2*256*40];

  const int tid = threadIdx.x, bid = blockIdx.x;
  const int hcb = bid >> 4, nm = bid & 15;
  const size_t Mbase = (size_t)nm * 256;
  const int hcBase = hcb * 32;
  const int w = tid >> 6, lane = tid & 63, ln = lane & 15, lq = lane >> 4;
  unsigned* const fl = flags + nm * FL_GRP;

  #pragma unroll
  for (int i = 0; i < 12; ++i){
    const int q = tid + i*512;
    const int rl = q >> 6, seg = q & 63;
    const int grow = (rl >> 5)*512 + hcBase + (rl & 31);
    *reinterpret_cast<uint4*>(&Ws[rl*520 + seg*8]) =
      *reinterpret_cast<const uint4*>(&W[(size_t)grow*512 + seg*8]);
  }
  if (USE_X && tid < 384){
    const int rl = tid >> 2, seg = tid & 3;
    const int grow = (rl >> 5)*512 + hcBase + (rl & 31);
    *reinterpret_cast<uint4*>(&Wxs[rl*40 + seg*8]) =
      *reinterpret_cast<const uint4*>(&Wx[(size_t)grow*32 + seg*8]);
  }

  auto stA = [&](int buf, int q, uint4 v){
    const int row = q >> 2, grp = q & 3;
    *reinterpret_cast<uint4*>(&As[buf + row*40 + grp*8]) = v;
  };

  float hreg[2][2][4];
  #pragma unroll
  for (int nt = 0; nt < 2; ++nt)
    #pragma unroll
    for (int mt = 0; mt < 2; ++mt)
      #pragma unroll
      for (int e = 0; e < 4; ++e) hreg[nt][mt][e] = 0.f;
  if (s0 > 0){
    #pragma unroll
    for (int nt = 0; nt < 2; ++nt){
      const int ch = hcBase + nt*16 + ln;
      #pragma unroll
      for (int mt = 0; mt < 2; ++mt)
        #pragma unroll
        for (int e = 0; e < 4; ++e){
          const size_t m = Mbase + w*32 + mt*16 + lq*4 + e;
          hreg[nt][mt][e] = hF[m*512 + ch];
        }
    }
  }

  for (int s = s0; s < s0 + nsteps; ++s){
    const int t = rev ? 27 - s : s;
    const bool first = (s == 0);
    const bool last  = (s == s0 + nsteps - 1);

    const us* hin; long hinm;
    us* hOut = nullptr;
    if (ymode == 1){ hin = y + (size_t)(rev ? t + 1 : t - 1) * 512; hinm = ymstride; }
    else if (ymode == 2){ hin = y + (size_t)((s - 1) & 3) * 512; hinm = ymstride; }
    else {
      hin  = hPP + (size_t)(s & 1) * PPH; hinm = 512;
      hOut = hPP + (size_t)((s & 1) ^ 1) * PPH;
    }

    auto ldH = [&](int kt, int q) -> uint4 {
      const int row = q >> 2, grp = q & 3;
      return *reinterpret_cast<const uint4*>(&hin[(Mbase + row)*hinm + kt*32 + grp*8]);
    };

    f4 acc[3][2][2] = {};
    f4 accNX[2][2] = {};

    // ---- h-independent work first: gxv hoist / x staging (overlaps the poll)
    us gxv[12][4];
    if (!USE_X){
      const us* gx = gxAll + (size_t)(s - s0) * PLANE;
      #pragma unroll
      for (int nt = 0; nt < 2; ++nt){
        const int ch = hcBase + nt*16 + ln;
        #pragma unroll
        for (int mt = 0; mt < 2; ++mt){
          #pragma unroll
          for (int e = 0; e < 4; ++e){
            const size_t m = Mbase + w*32 + mt*16 + lq*4 + e;
            const us* gxr = gx + m*1536;
            gxv[0 + nt*2 + mt][e] = gxr[ch];
            gxv[4 + nt*2 + mt][e] = gxr[512 + ch];
            gxv[8 + nt*2 + mt][e] = gxr[1024 + ch];
          }
        }
      }
    }
    if (USE_X){
      #pragma unroll
      for (int i = 0; i < 2; ++i){
        const int q = tid + i*512;
        const int row = q >> 2, grp = q & 3;
        uint4 v = *reinterpret_cast<const uint4*>(
          &xb[((Mbase + row)*28 + (size_t)t)*32 + grp*8]);
        stA(0, q, v);
      }
    }
    __syncthreads();   // x slab visible (also orders W-slab load on s0 iter)

    // ---- x-projection K-tile (K=32, Wxs pinned) — still before the poll
    if (USE_X){
      bf8 a0 = ldb(&As[(w*32 +  0 + ln)*40 + lq*8]);
      bf8 a1 = ldb(&As[(w*32 + 16 + ln)*40 + lq*8]);
      #pragma unroll
      for (int g = 0; g < 3; ++g){
        #pragma unroll
        for (int nt = 0; nt < 2; ++nt){
          bf8 b = ldb(&Wxs[(g*32 + nt*16 + ln)*40 + lq*8]);
          if (g == 2){
            accNX[nt][0] = mfma(a0, b, accNX[nt][0]);
            accNX[nt][1] = mfma(a1, b, accNX[nt][1]);
          } else {
            acc[g][nt][0] = mfma(a0, b, acc[g][nt][0]);
            acc[g][nt][1] = mfma(a1, b, acc[g][nt][1]);
          }
        }
      }
    }

    // ---- NOW wait for the group to have finished step s-1 (skip at chunk start)
    if (s > s0){
      if (tid < 16){
        const unsigned tgt = (unsigned)s;
        int guard = 0;
        while (__hip_atomic_load(fl + tid, __ATOMIC_RELAXED,
                                 __HIP_MEMORY_SCOPE_AGENT) < tgt){
          __builtin_amdgcn_s_sleep(1);
          if (++guard > (1 << 18)) break;   // watchdog: never hang the queue
        }
      }
      __syncthreads();
    }

    // ---- h @ Whh^T, 16 K-tiles, A double-buffered (round-8 loop, unchanged)
    if (!first){
      const int B0 = USE_X ? 10240 : 0;
      stA(B0, tid, ldH(0, tid)); stA(B0, tid + 512, ldH(0, tid + 512));
      uint4 s1a = ldH(1, tid), s1b = ldH(1, tid + 512);
      uint4 s2a = ldH(2, tid), s2b = ldH(2, tid + 512);
      __syncthreads();

      for (int kt = 0; kt < 16; ++kt){
        const int buf = B0 ^ ((kt & 1) * 10240);
        bf8 a0 = ldb(&As[buf + (w*32 +  0 + ln)*40 + lq*8]);
        bf8 a1 = ldb(&As[buf + (w*32 + 16 + ln)*40 + lq*8]);
        const int kc = kt*32 + lq*8;
        #pragma unroll
        for (int g = 0; g < 3; ++g){
          #pragma unroll
          for (int nt = 0; nt < 2; ++nt){
            bf8 b = ldb(&Ws[(g*32 + nt*16 + ln)*520 + kc]);
            acc[g][nt][0] = mfma(a0, b, acc[g][nt][0]);
            acc[g][nt][1] = mfma(a1, b, acc[g][nt][1]);
          }
        }
        if (kt < 15){
          stA(buf ^ 10240, tid, s1a); stA(buf ^ 10240, tid + 512, s1b);
          s1a = s2a; s1b = s2b;
          if (kt + 3 < 16){ s2a = ldH(kt + 3, tid); s2b = ldH(kt + 3, tid + 512); }
          __syncthreads();
        }
      }
    }

    // ---- gate epilogue (hprev from registers; h plane write = y slice)
    #pragma unroll
    for (int nt = 0; nt < 2; ++nt){
      const int ch = hcBase + nt*16 + ln;
      const float br = brz[ch], bz = brz[512 + ch], bi = bni[ch], bh = bnh[ch];
      #pragma unroll
      for (int mt = 0; mt < 2; ++mt){
        #pragma unroll
        for (int e = 0; e < 4; ++e){
          const size_t m = Mbase + w*32 + mt*16 + lq*4 + e;
          float rr = acc[0][nt][mt][e] + br;
          float zz = acc[1][nt][mt][e] + bz;
          float xr = accNX[nt][mt][e];
          if (!USE_X){
            rr += bf2f(gxv[0 + nt*2 + mt][e]);
            zz += bf2f(gxv[4 + nt*2 + mt][e]);
            xr += bf2f(gxv[8 + nt*2 + mt][e]);
          }
          float r = sigm(rr);
          float z = sigm(zz);
          float n = tanh_fast(xr + bi + r*(acc[2][nt][mt][e] + bh));
          float hprev = first ? 0.f : hreg[nt][mt][e];
          float h = n + z*(hprev - n);
          hreg[nt][mt][e] = h;
          if (last && hF) hF[m*512 + ch] = h;
          us hb = f2bf(h);
          if (ymode == 0)      hOut[m*512 + ch] = hb;
          else if (ymode == 1) y[m*ymstride + (size_t)t*512 + ch] = hb;
          else                 y[m*ymstride + (size_t)(s - s0)*512 + ch] = hb;
        }
      }
    }

    // ---- publish only (poll happens at the top of the next step)
    if (!last){
      __syncthreads();   // every wave: vmcnt(0)+barrier -> all stores in XCD L2
      if (tid == 0)
        __hip_atomic_store(fl + hcb, (unsigned)(s + 1),
                           __ATOMIC_RELAXED, __HIP_MEMORY_SCOPE_AGENT);
    }
  }
}

// ---------------- l1 backward single step: elementwise gates from gxb (h=0) ----
__global__ void gate1b_kernel(
  const us* __restrict__ gxb, const float* __restrict__ brz,
  const float* __restrict__ bni, const float* __restrict__ bnh,
  us* __restrict__ h1b)
{
  const int i = blockIdx.x * blockDim.x + threadIdx.x;
  if (i >= 4096*512) return;
  const int m = i >> 9, ch = i & 511;
  const us* g = gxb + (size_t)m*1536;
  float r = sigm(bf2f(g[ch]) + brz[ch]);
  float z = sigm(bf2f(g[512 + ch]) + brz[512 + ch]);
  float n = tanh_fast(bf2f(g[1024 + ch]) + bni[ch] + r*bnh[ch]);
  h1b[i] = f2bf((1.f - z)*n);
}

// ---------------- head: [h1f|h1b] -> fc1 -> bn/relu -> fc2 -> log_softmax ----
__global__ __launch_bounds__(512) void head_kernel(
  const us* __restrict__ h1f, const us* __restrict__ h1b,
  const us* __restrict__ fc1w, const us* __restrict__ fc2wp,
  const float* __restrict__ sc2, const float* __restrict__ sh2,
  const float* __restrict__ fc2b, float* __restrict__ out)
{
  constexpr int APS = 1048;
  __shared__ us As[32 * APS];
  __shared__ us actS[32 * 264];
  __shared__ float lg[32 * 16];
  const int tid = threadIdx.x;
  const size_t row0 = (size_t)blockIdx.x * 32;
  const int w = tid >> 6, lane = tid & 63, ln = lane & 15, lq = lane >> 4;

  for (int i = tid; i < 32*128; i += 512){
    int r = i >> 7, g = i & 127, col = g*8;
    uint4 v = (col < 512)
      ? *reinterpret_cast<const uint4*>(h1f + (row0 + r)*512 + col)
      : *reinterpret_cast<const uint4*>(h1b + (row0 + r)*512 + (col - 512));
    *reinterpret_cast<uint4*>(&As[r*APS + col]) = v;
  }
  __syncthreads();

  {
    f4 acc[2][2] = {};
    for (int kt = 0; kt < 32; ++kt){
      const int kc = kt*32 + lq*8;
      bf8 a0 = ldb(&As[ln*APS + kc]);
      bf8 a1 = ldb(&As[(16 + ln)*APS + kc]);
      #pragma unroll
      for (int nt = 0; nt < 2; ++nt){
        const int col = w*32 + nt*16 + ln;
        bf8 b = ldb(&fc1w[(size_t)col*1024 + kc]);
        acc[0][nt] = mfma(a0, b, acc[0][nt]);
        acc[1][nt] = mfma(a1, b, acc[1][nt]);
      }
    }
    #pragma unroll
    for (int nt = 0; nt < 2; ++nt){
      const int col = w*32 + nt*16 + ln;
      const float sc = sc2[col], sh = sh2[col];
      #pragma unroll
      for (int mt = 0; mt < 2; ++mt)
        #pragma unroll
        for (int e = 0; e < 4; ++e){
          float v = fmaxf(acc[mt][nt][e]*sc + sh, 0.f);
          actS[(mt*16 + lq*4 + e)*264 + col] = f2bf(v);
        }
    }
    __syncthreads();
  }

  if (w == 0){
    f4 acc[2] = {};
    for (int kt = 0; kt < 8; ++kt){
      const int kc = kt*32 + lq*8;
      bf8 a0 = ldb(&actS[ln*264 + kc]);
      bf8 a1 = ldb(&actS[(16 + ln)*264 + kc]);
      bf8 b  = ldb(&fc2wp[ln*256 + kc]);
      acc[0] = mfma(a0, b, acc[0]);
      acc[1] = mfma(a1, b, acc[1]);
    }
    const float bb = fc2b[ln];
    #pragma unroll
    for (int mt = 0; mt < 2; ++mt)
      #pragma unroll
      for (int e = 0; e < 4; ++e)
        lg[(mt*16 + lq*4 + e)*16 + ln] = acc[mt][e] + bb;
  }
  __syncthreads();
  if (tid < 32){
    const int r = tid;
    float mx = -1e30f;
    for (int cc = 0; cc < 10; ++cc) mx = fmaxf(mx, lg[r*16 + cc]);
    float sum = 0.f;
    for (int cc = 0; cc < 10; ++cc) sum += __expf(lg[r*16 + cc] - mx);
    const float lse = mx + logf(sum);
    for (int cc = 0; cc < 10; ++cc)
      out[(row0 + r)*10 + cc] = lg[r*16 + cc] - lse;
  }
}

// ---------------- launch ----------------
extern "C" void kernel_launch(void* const* d_in, const int* in_sizes, int n_in,
                              void* d_out, int out_size, void* d_ws, size_t ws_size,
                              hipStream_t stream)
{
  (void)in_sizes; (void)n_in; (void)out_size; (void)ws_size;
  char* ws = (char*)d_ws;
  auto US = [&](size_t off){ return (us*)(ws + off); };
  auto FP = [&](size_t off){ return (float*)(ws + off); };

  const float* x      = (const float*)d_in[0];
  const float* Wih0   = (const float*)d_in[1];
  const float* Whh0   = (const float*)d_in[2];
  const float* bih0   = (const float*)d_in[3];
  const float* bhh0   = (const float*)d_in[4];
  const float* Wih0r  = (const float*)d_in[5];
  const float* Whh0r  = (const float*)d_in[6];
  const float* bih0r  = (const float*)d_in[7];
  const float* bhh0r  = (const float*)d_in[8];
  const float* Wih1   = (const float*)d_in[9];
  const float* Whh1   = (const float*)d_in[10];
  const float* bih1   = (const float*)d_in[11];
  const float* bhh1   = (const float*)d_in[12];
  const float* Wih1r  = (const float*)d_in[13];
  // d_in[14] (W_hh_l1r) unused: backward layer-1 runs exactly one step from h=0.
  const float* bih1r  = (const float*)d_in[15];
  const float* bhh1r  = (const float*)d_in[16];
  const float* fc1w   = (const float*)d_in[17];
  const float* fc1b   = (const float*)d_in[18];
  const float* gma    = (const float*)d_in[19];
  const float* bta    = (const float*)d_in[20];
  const float* mean   = (const float*)d_in[21];
  const float* var    = (const float*)d_in[22];
  const float* fc2w   = (const float*)d_in[23];
  const float* fc2b   = (const float*)d_in[24];

  prep_kernel<<<512, 256, 0, stream>>>(
    x, Wih0, Whh0, bih0, bhh0, Wih0r, Whh0r, bih0r, bhh0r,
    Wih1, Whh1, bih1, bhh1, Wih1r, bih1r, bhh1r,
    fc1w, fc1b, gma, bta, mean, var, fc2w, fc2b,
    US(OFF_WHH0F), US(OFF_WHH0R), US(OFF_WIH0F), US(OFF_WIH0R),
    US(OFF_WIH1), US(OFF_WHH1), US(OFF_WIH1R), US(OFF_FC1W), US(OFF_FC2W),
    FP(OFF_BRZ0), FP(OFF_BNIH0), FP(OFF_BNHH0),
    FP(OFF_BRZ1), FP(OFF_BNIH1), FP(OFF_BNHH1),
    FP(OFF_BRZ1R), FP(OFF_BNIH1R), FP(OFF_BNHH1R),
    FP(OFF_SC2), FP(OFF_SH2), FP(OFF_FC2B),
    US(OFF_XB), (unsigned*)(ws + OFF_BAR));

  us* y0b  = US(OFF_Y0B);
  us* y0fc = US(OFF_Y0FC);
  us* gx   = US(OFF_GX);
  us* h1bf = US(OFF_H1BF);
  us* xb   = US(OFF_XB);
  unsigned* fl = (unsigned*)(ws + OFF_BAR);

  // ---- phase A: layer-0 backward — one persistent launch; h lives in y0b slices
  gru_coop_kernel<1><<<256, 512, 0, stream>>>(
    US(OFF_WHH0R), US(OFF_WIH0R), xb, nullptr,
    nullptr, nullptr, y0b, 28ll*512, 1,
    FP(OFF_BRZ0) + 1024, FP(OFF_BNIH0) + 512, FP(OFF_BNHH0) + 512,
    0, 28, 1, fl + 0*FL_SLOT);

  // ---- phase B: l0f chunk (h in y0fc ring) + gx1 gemm + l1f chunk ----
  for (int c = 0; c < 7; ++c){
    const int t0 = 4*c;
    gru_coop_kernel<1><<<256, 512, 0, stream>>>(
      US(OFF_WHH0F), US(OFF_WIH0F), xb, nullptr,
      nullptr, FP(OFF_H0F32), y0fc, 4ll*512, 2,
      FP(OFF_BRZ0), FP(OFF_BNIH0), FP(OFF_BNHH0),
      t0, 4, 0, fl + 1*FL_SLOT);
    // gx1[sl] = [y0fc[:,sl,:] | y0b[:,t0+sl,:]] @ Wih1^T  (K=1024, nk=32)
    gemm_kernel<<<128*12, 256, 0, stream>>>(
      y0fc, 4ll*512, 512, 512,
      y0b + t0*512, 28ll*512, 512,
      US(OFF_WIH1), 1024, 32, 2, 128, gx, PLANE);
    gru_coop_kernel<0><<<256, 512, 0, stream>>>(
      US(OFF_WHH1), nullptr, nullptr, gx,
      h1bf, FP(OFF_H1F32), nullptr, 0, 0,
      FP(OFF_BRZ1), FP(OFF_BNIH1), FP(OFF_BNHH1),
      t0, 4, 0, fl + 2*FL_SLOT);
  }

  // ---- layer-1 backward: gxb = [h0f_27 | y0b_27] @ Wih1r^T, then gates (h=0) ----
  // h0f final state (t=27) = y0fc slice 3 after the last l0f chunk.
  gemm_kernel<<<32*12, 256, 0, stream>>>(
    y0fc + 3*512, 4ll*512, 0, 512,
    y0b + 27*512, 28ll*512, 0,
    US(OFF_WIH1R), 1024, 32, 0, 32, gx, 0);
  gate1b_kernel<<<8192, 256, 0, stream>>>(
    gx, FP(OFF_BRZ1R), FP(OFF_BNIH1R), FP(OFF_BNHH1R), US(OFF_H1B));

  // ---- head (h1f final is pp buffer 0 after 28 steps) ----
  head_kernel<<<128, 512, 0, stream>>>(
    h1bf, US(OFF_H1B), US(OFF_FC1W), US(OFF_FC2W),
    FP(OFF_SC2), FP(OFF_SH2), FP(OFF_FC2B), (float*)d_out);
}